// Round 6
// baseline (281.586 us; speedup 1.0000x reference)
//
#include <hip/hip_runtime.h>
#include <hip/hip_bf16.h>

// Problem constants (from reference)
#define B_   4
#define S_   2048
#define DIN  1024
#define DH   1024
#define DOUT 1024

typedef __attribute__((ext_vector_type(8))) __bf16 bf16x8;
typedef __attribute__((ext_vector_type(4))) float floatx4;
typedef unsigned short u16;
typedef unsigned int u32;

__device__ inline u16 f2bf(float f) {
  union { float f; u32 u; } x; x.f = f;
  u32 r = x.u + 0x7fffu + ((x.u >> 16) & 1u);  // RTNE
  return (u16)(r >> 16);
}

#define BARRIER() do { asm volatile("" ::: "memory"); __builtin_amdgcn_s_barrier(); \
                       asm volatile("" ::: "memory"); } while (0)
#define WAITVM(N) asm volatile("s_waitcnt vmcnt(" #N ")" ::: "memory")

// ---------------------------------------------------------------------------
// Fused fp32 -> bf16 cast for all 7 tensors (dst regions contiguous in ws)
// ---------------------------------------------------------------------------
__global__ __launch_bounds__(256)
void cast_all(const float* __restrict__ q, const float* __restrict__ k,
              const float* __restrict__ v, const float* __restrict__ w0,
              const float* __restrict__ w1, const float* __restrict__ w2,
              const float* __restrict__ w3, u16* __restrict__ dst) {
  const long nQ = (long)B_ * S_ * DIN;   // 8,388,608
  const long nW = (long)DH * DIN;        // 1,048,576
  long b = blockIdx.x;
  const float* src; long doff;
  if (b < 8192)       { src = q;  doff = 0;            }
  else if (b < 16384) { src = k;  doff = nQ;     b -= 8192;  }
  else if (b < 24576) { src = v;  doff = 2 * nQ; b -= 16384; }
  else if (b < 25600) { src = w0; doff = 3 * nQ; b -= 24576; }
  else if (b < 26624) { src = w1; doff = 3 * nQ + nW;     b -= 25600; }
  else if (b < 27648) { src = w2; doff = 3 * nQ + 2 * nW; b -= 26624; }
  else                { src = w3; doff = 3 * nQ + 3 * nW; b -= 27648; }
  long i = b * 256 + threadIdx.x;        // float4 index within region
  float4 vv = ((const float4*)src)[i];
  ushort4 o;
  o.x = f2bf(vv.x); o.y = f2bf(vv.y); o.z = f2bf(vv.z); o.w = f2bf(vv.w);
  ((ushort4*)(dst + doff))[i] = o;
}

// ---------------------------------------------------------------------------
// gather 3 bias vectors into one contiguous [3][DH] buffer
// ---------------------------------------------------------------------------
__global__ __launch_bounds__(256)
void gather_bias(const float* __restrict__ b0, const float* __restrict__ b1,
                 const float* __restrict__ b2, float* __restrict__ dst) {
  int i = blockIdx.x * 256 + threadIdx.x;
  if (i < DH) dst[i] = b0[i];
  else if (i < 2 * DH) dst[i] = b1[i - DH];
  else if (i < 3 * DH) dst[i] = b2[i - 2 * DH];
}

// ---------------------------------------------------------------------------
// bf16 32x32-tile transpose ([S_][1024] -> [1024][S_] per batch)
// ---------------------------------------------------------------------------
__global__ __launch_bounds__(256)
void transpose_bf16(const u16* __restrict__ in, u16* __restrict__ out) {
  __shared__ u16 t[32][33];
  const int b = blockIdx.z;
  const int r0 = blockIdx.y * 32, c0 = blockIdx.x * 32;
  const int tx = threadIdx.x & 31, ty = threadIdx.x >> 5;  // 32 x 8
  const u16* ib = in + (long)b * S_ * DH;
  u16* ob = out + (long)b * DH * S_;
#pragma unroll
  for (int i = 0; i < 4; ++i) {
    int r = ty + i * 8;
    t[r][tx] = ib[(long)(r0 + r) * DH + (c0 + tx)];
  }
  __syncthreads();
#pragma unroll
  for (int i = 0; i < 4; ++i) {
    int r = ty + i * 8;
    ob[(long)(c0 + r) * S_ + (r0 + tx)] = t[tx][r];
  }
}

// ---------------------------------------------------------------------------
// sumrows: invs[row] = 1 / sum_{g<16} Psum[row][g]   (B_*S_ rows)
// ---------------------------------------------------------------------------
__global__ __launch_bounds__(256)
void sumrows(const float* __restrict__ Psum, float* __restrict__ invs) {
  int i = blockIdx.x * 256 + threadIdx.x;
  const float4* p = (const float4*)(Psum + (long)i * 16);
  float4 a = p[0], b = p[1], c = p[2], d = p[3];
  float s = (a.x + a.y + a.z + a.w) + (b.x + b.y + b.z + b.w)
          + (c.x + c.y + c.z + c.w) + (d.x + d.y + d.z + d.w);
  invs[i] = 1.0f / s;
}

// ---------------------------------------------------------------------------
// gemm: BM=256 x BN=128 / BK=32 / 4 waves (2Mx2N; 128x64 per wave) bf16 B^T
// GEMM, m97-style dbuf loop: 1 barrier + vmcnt(0) drain per K-tile.
//   C[M,N] = A[M,K] @ B[N,K]^T (+epilogue).  M%256==0, N%128==0, K%32==0.
// Key design points (from R5 post-mortem):
//  - 48 KB LDS -> 2 blocks/CU: co-resident block's MFMA covers the per-tile
//    staging drain (m97/m114 TLP mechanism) -- the thing 1-block/CU configs
//    structurally cannot do.
//  - 128x64 per-wave tile = 23 B/kFLOP LDS-read (m201-class) so LDS BW
//    doesn't cap MfmaUtil below ~60%.
//  - linear LDS, per-m-frag wave read = dense aligned 1KB -> conflict-free;
//    staging dest linear (rule 21), global src 64B-per-4-lane coalesced.
//  - T1 bijective XCD-chunk swizzle on a flat grid (size % 8 == 0).
// ---------------------------------------------------------------------------
#define EPI_BF16_BIAS 0   // C u16  : v + bias[bz*sBias+col]
#define EPI_BF16      1   // C u16  : v
#define EPI_PEXP      2   // C u16  : mask ? exp(v*scale) : 0 ; Psum partials
#define EPI_F32_SB    3   // C f32  : v * rowinv[bz*S_+row] + bias[col]

template <int EPI>
__global__ __launch_bounds__(256, 2)
void gemm(const u16* __restrict__ A, const u16* __restrict__ Bm,
          void* __restrict__ C, const float* __restrict__ bias,
          const int* __restrict__ mask, const float* __restrict__ rowinv,
          float* __restrict__ Psum,
          int M, int N, int K, float scale,
          long sA, long sB, long sC, long sMask, long sBias,
          int nbx, int nby) {
  __shared__ u16 lds_[2 * 12288];   // [buf][A 8192 u16 | B 4096 u16] = 48 KB

  const int tid = threadIdx.x;
  const int w = tid >> 6, l = tid & 63;
  const int wr = w >> 1, wc = w & 1;
  const int lr = l & 15, q = l >> 4;

  // T1: bijective XCD-chunk swizzle (grid % 8 == 0)
  const int flat = blockIdx.x;
  const int swz = (flat & 7) * ((int)gridDim.x >> 3) + (flat >> 3);
  const int bx = swz % nbx;
  const int rest = swz / nbx;
  const int by = rest % nby;
  const int bz = rest / nby;

  const long arow0 = (long)by * 256;
  const long bcol0 = (long)bx * 128;
  const u16* Ab = A + bz * sA + arow0 * K;
  const u16* Bb = Bm + bz * sB + bcol0 * K;
  const int nt = K >> 5;

  const int r0 = tid >> 2;          // staging row within 64-row group
  const int ks8 = (tid & 3) * 8;    // staging 16B-slot element offset

  // Stage K-tile TT (A 16KB + B 8KB) into buf TT&1. Dest: linear, wave writes
  // dense 1KB. Src: 4 lanes cover one row's 64B k-slice (coalesced).
#define STAGE(TT) do {                                                        \
    const int _b = (TT) & 1;                                                  \
    const long _k0 = (long)(TT) * 32;                                         \
    _Pragma("unroll")                                                         \
    for (int _i = 0; _i < 4; ++_i) {   /* A: 256 rows */                      \
      const u16* _s = Ab + (long)(_i * 64 + r0) * K + _k0 + ks8;              \
      u16* _d = &lds_[_b * 12288 + (_i * 256 + tid) * 8];                     \
      __builtin_amdgcn_global_load_lds(                                       \
         (const __attribute__((address_space(1))) u32*)_s,                    \
         (__attribute__((address_space(3))) u32*)_d, 16, 0, 0);               \
    }                                                                         \
    _Pragma("unroll")                                                         \
    for (int _i = 0; _i < 2; ++_i) {   /* B: 128 rows */                      \
      const u16* _s = Bb + (long)(_i * 64 + r0) * K + _k0 + ks8;              \
      u16* _d = &lds_[_b * 12288 + 8192 + (_i * 256 + tid) * 8];              \
      __builtin_amdgcn_global_load_lds(                                       \
         (const __attribute__((address_space(1))) u32*)_s,                    \
         (__attribute__((address_space(3))) u32*)_d, 16, 0, 0);               \
    }                                                                         \
  } while (0)

  floatx4 acc[8][4] = {};

  STAGE(0);
  WAITVM(0);
  BARRIER();

  for (int t = 0; t < nt; ++t) {
    const int buf = t & 1;
    bf16x8 a[8], b[4];
#pragma unroll
    for (int m = 0; m < 8; ++m)
      a[m] = *(const bf16x8*)&lds_[buf * 12288
                                   + (wr * 128 + m * 16 + lr) * 32 + q * 8];
#pragma unroll
    for (int n = 0; n < 4; ++n)
      b[n] = *(const bf16x8*)&lds_[buf * 12288 + 8192
                                   + (wc * 64 + n * 16 + lr) * 32 + q * 8];
    if (t + 1 < nt) STAGE(t + 1);
#pragma unroll
    for (int n = 0; n < 4; ++n)
#pragma unroll
      for (int m = 0; m < 8; ++m)
        acc[m][n] = __builtin_amdgcn_mfma_f32_16x16x32_bf16(a[m], b[n], acc[m][n], 0, 0, 0);
    WAITVM(0);   // staged tile t+1 landed; co-resident block covers the drain
    BARRIER();
  }
#undef STAGE

  // ---- epilogue. C/D layout: col = l&15, row = (l>>4)*4 + reg  [m89]
  const int r4 = q * 4;
  if constexpr (EPI == EPI_PEXP) {
    float rsum[8][4];
#pragma unroll
    for (int mf = 0; mf < 8; ++mf)
#pragma unroll
      for (int r = 0; r < 4; ++r) rsum[mf][r] = 0.f;
#pragma unroll
    for (int mf = 0; mf < 8; ++mf)
#pragma unroll
      for (int nf = 0; nf < 4; ++nf)
#pragma unroll
        for (int r = 0; r < 4; ++r) {
          const long row = arow0 + wr * 128 + mf * 16 + r4 + r;
          const long col = bcol0 + wc * 64 + nf * 16 + lr;
          const int mk = mask[bz * sMask + row * (long)N + col];
          float p = 0.f;
          if (mk != 0) p = __expf(acc[mf][nf][r] * scale);
          ((u16*)C)[bz * sC + row * N + col] = f2bf(p);
          rsum[mf][r] += p;
        }
    // reduce 16 lr-lanes -> lane lr==0; cross-wave (wc 0/1) via LDS
    float* sc = (float*)lds_;   // [256 rows][2 wc] f32 (K-loop LDS is dead)
#pragma unroll
    for (int mf = 0; mf < 8; ++mf)
#pragma unroll
      for (int r = 0; r < 4; ++r) {
        float s = rsum[mf][r];
        s += __shfl_xor(s, 1); s += __shfl_xor(s, 2);
        s += __shfl_xor(s, 4); s += __shfl_xor(s, 8);
        if (lr == 0) sc[(wr * 128 + mf * 16 + r4 + r) * 2 + wc] = s;
      }
    __syncthreads();
    if (tid < 256) {
      float tot = sc[tid * 2] + sc[tid * 2 + 1];
      Psum[((long)bz * S_ + arow0 + tid) * 16 + bx] = tot;
    }
  } else {
#pragma unroll
    for (int mf = 0; mf < 8; ++mf)
#pragma unroll
      for (int nf = 0; nf < 4; ++nf)
#pragma unroll
        for (int r = 0; r < 4; ++r) {
          const long row = arow0 + wr * 128 + mf * 16 + r4 + r;
          const long col = bcol0 + wc * 64 + nf * 16 + lr;
          float v = acc[mf][nf][r];
          if constexpr (EPI == EPI_BF16_BIAS) {
            v += bias[bz * sBias + col];
            ((u16*)C)[bz * sC + row * N + col] = f2bf(v);
          } else if constexpr (EPI == EPI_BF16) {
            ((u16*)C)[bz * sC + row * N + col] = f2bf(v);
          } else {  // EPI_F32_SB: out = v * rowinv + bias
            v = v * rowinv[(long)bz * S_ + row] + bias[col];
            ((float*)C)[bz * sC + row * N + col] = v;
          }
        }
  }
}

// ---------------------------------------------------------------------------
extern "C" void kernel_launch(void* const* d_in, const int* in_sizes, int n_in,
                              void* d_out, int out_size, void* d_ws, size_t ws_size,
                              hipStream_t stream) {
  const float* q    = (const float*)d_in[0];
  const float* k    = (const float*)d_in[1];
  const float* v    = (const float*)d_in[2];
  const int*   mask = (const int*)d_in[3];
  const float* Wq   = (const float*)d_in[4];
  const float* bq   = (const float*)d_in[5];
  const float* Wk   = (const float*)d_in[6];
  const float* bk   = (const float*)d_in[7];
  const float* Wv   = (const float*)d_in[8];
  const float* bv   = (const float*)d_in[9];
  const float* Wo   = (const float*)d_in[10];
  const float* bo   = (const float*)d_in[11];

  const long BS = (long)B_ * S_;      // 8192
  const long nQ = BS * DH;            // 8,388,608
  const long nW = (long)DH * DIN;     // 1,048,576
  const long nE = (long)B_ * S_ * S_; // 16,777,216

  char* ws = (char*)d_ws;
  size_t off = 0;
  auto alloc = [&](size_t bytes) {
    void* p = ws + off; off += (bytes + 255) & ~(size_t)255; return p;
  };

  // NOTE: qb..wob must stay CONTIGUOUS in this order (cast_all assumes it).
  u16* qb   = (u16*)alloc(nQ * 2);
  u16* kb   = (u16*)alloc(nQ * 2);
  u16* vb   = (u16*)alloc(nQ * 2);
  u16* wqb  = (u16*)alloc(nW * 2);
  u16* wkb  = (u16*)alloc(nW * 2);
  u16* wvb  = (u16*)alloc(nW * 2);
  u16* wob  = (u16*)alloc(nW * 2);
  u16* Qb   = (u16*)alloc(nQ * 2);
  u16* Kbf  = (u16*)alloc(nQ * 2);
  u16* Vb   = (u16*)alloc(nQ * 2);
  u16* P    = (u16*)alloc(nE * 2);           // exp(e) unnormalized, bf16
  u16* VW   = (u16*)alloc(nQ * 2);           // V @ Wo^T (bf16)
  u16* VWT  = (u16*)alloc(nQ * 2);           // (V @ Wo^T)^T per batch
  float* Psum = (float*)alloc(BS * 16 * 4);  // per-block row partials
  float* invs = (float*)alloc(BS * 4);       // 1/rowsum
  float* bcat = (float*)alloc(3 * DH * 4);
  (void)wkb; (void)wvb;

  // 1. fused casts + bias gather
  cast_all<<<dim3(28672), 256, 0, stream>>>(q, k, v, Wq, Wk, Wv, Wo, qb);
  gather_bias<<<dim3(12), 256, 0, stream>>>(bq, bk, bv, bcat);

  // 2. QKV projections, batched z=3: 8x32x3 = 768 flat blocks
  gemm<EPI_BF16_BIAS><<<dim3(768), 256, 0, stream>>>(qb, wqb, Qb, bcat,
      nullptr, nullptr, nullptr,
      (int)BS, DH, DIN, 1.f, nQ, nW, nQ, 0, DH, 8, 32);

  // 3. VW = V @ Wo^T  (z=4: M=2048, N=1024, K=1024) -> 8x8x4 = 256 blocks
  gemm<EPI_BF16><<<dim3(256), 256, 0, stream>>>(Vb, wob, VW, nullptr,
      nullptr, nullptr, nullptr,
      S_, DOUT, DH, 1.f, (long)S_ * DH, 0, (long)S_ * DOUT, 0, 0, 8, 8);

  // 4. VW -> VW^T per batch
  {
    dim3 g(DOUT / 32, S_ / 32, B_);
    transpose_bf16<<<g, 256, 0, stream>>>(VW, VWT);
  }

  // 5. P = exp((Q K^T)/32) masked->0 (bf16) + row partials: 16x8x4 = 512
  gemm<EPI_PEXP><<<dim3(512), 256, 0, stream>>>(Qb, Kbf, P, nullptr,
      mask, nullptr, Psum,
      S_, S_, DH, 0.03125f,
      (long)S_ * DH, (long)S_ * DH, (long)S_ * S_, (long)S_ * S_, 0, 16, 8);

  // 6. row-sum reciprocals
  sumrows<<<dim3(32), 256, 0, stream>>>(Psum, invs);

  // 7. out = diag(invs) * (P @ VWT^T) + bo  (z=4, K=2048) -> 8x8x4 = 256
  gemm<EPI_F32_SB><<<dim3(256), 256, 0, stream>>>(P, VWT, d_out, bo,
      nullptr, invs, nullptr,
      S_, DOUT, S_, 1.f,
      (long)S_ * S_, (long)DOUT * S_, (long)S_ * DOUT, 0, 0, 8, 8);
}

// Round 8
// 267.312 us; speedup vs baseline: 1.0534x; 1.0534x over previous
//
#include <hip/hip_runtime.h>
#include <hip/hip_bf16.h>

// Problem constants (from reference)
#define B_   4
#define S_   2048
#define DIN  1024
#define DH   1024
#define DOUT 1024

typedef __attribute__((ext_vector_type(8))) __bf16 bf16x8;
typedef __attribute__((ext_vector_type(4))) float floatx4;
typedef unsigned short u16;
typedef unsigned int u32;

__device__ inline u16 f2bf(float f) {
  union { float f; u32 u; } x; x.f = f;
  u32 r = x.u + 0x7fffu + ((x.u >> 16) & 1u);  // RTNE
  return (u16)(r >> 16);
}

#define GLOAD(SRC, DST) __builtin_amdgcn_global_load_lds(                     \
    (const __attribute__((address_space(1))) u32*)(SRC),                      \
    (__attribute__((address_space(3))) u32*)(DST), 16, 0, 0)
#define WAITVM0() asm volatile("s_waitcnt vmcnt(0)" ::: "memory")

// ---------------------------------------------------------------------------
// Fused fp32 -> bf16 cast for all 7 tensors (dst regions contiguous in ws)
// ---------------------------------------------------------------------------
__global__ __launch_bounds__(256)
void cast_all(const float* __restrict__ q, const float* __restrict__ k,
              const float* __restrict__ v, const float* __restrict__ w0,
              const float* __restrict__ w1, const float* __restrict__ w2,
              const float* __restrict__ w3, u16* __restrict__ dst) {
  const long nQ = (long)B_ * S_ * DIN;   // 8,388,608
  const long nW = (long)DH * DIN;        // 1,048,576
  long b = blockIdx.x;
  const float* src; long doff;
  if (b < 8192)       { src = q;  doff = 0;            }
  else if (b < 16384) { src = k;  doff = nQ;     b -= 8192;  }
  else if (b < 24576) { src = v;  doff = 2 * nQ; b -= 16384; }
  else if (b < 25600) { src = w0; doff = 3 * nQ; b -= 24576; }
  else if (b < 26624) { src = w1; doff = 3 * nQ + nW;     b -= 25600; }
  else if (b < 27648) { src = w2; doff = 3 * nQ + 2 * nW; b -= 26624; }
  else                { src = w3; doff = 3 * nQ + 3 * nW; b -= 27648; }
  long i = b * 256 + threadIdx.x;        // float4 index within region
  float4 vv = ((const float4*)src)[i];
  ushort4 o;
  o.x = f2bf(vv.x); o.y = f2bf(vv.y); o.z = f2bf(vv.z); o.w = f2bf(vv.w);
  ((ushort4*)(dst + doff))[i] = o;
}

// ---------------------------------------------------------------------------
// gather 3 bias vectors into one contiguous [3][DH] buffer
// ---------------------------------------------------------------------------
__global__ __launch_bounds__(256)
void gather_bias(const float* __restrict__ b0, const float* __restrict__ b1,
                 const float* __restrict__ b2, float* __restrict__ dst) {
  int i = blockIdx.x * 256 + threadIdx.x;
  if (i < DH) dst[i] = b0[i];
  else if (i < 2 * DH) dst[i] = b1[i - DH];
  else if (i < 3 * DH) dst[i] = b2[i - 2 * DH];
}

// ---------------------------------------------------------------------------
// bf16 32x32-tile transpose (V -> V^T so PV becomes a B^T GEMM)
// ---------------------------------------------------------------------------
__global__ __launch_bounds__(256)
void transpose_bf16(const u16* __restrict__ in, u16* __restrict__ out) {
  __shared__ u16 t[32][33];
  const int b = blockIdx.z;
  const int r0 = blockIdx.y * 32, c0 = blockIdx.x * 32;
  const int tx = threadIdx.x & 31, ty = threadIdx.x >> 5;  // 32 x 8
  const u16* ib = in + (long)b * S_ * DH;
  u16* ob = out + (long)b * DH * S_;
#pragma unroll
  for (int i = 0; i < 4; ++i) {
    int r = ty + i * 8;
    t[r][tx] = ib[(long)(r0 + r) * DH + (c0 + tx)];
  }
  __syncthreads();
#pragma unroll
  for (int i = 0; i < 4; ++i) {
    int r = ty + i * 8;
    ob[(long)(c0 + r) * S_ + (r0 + tx)] = t[tx][r];
  }
}

// ---------------------------------------------------------------------------
// sumrows: invs[row] = 1 / sum_{g<16} Psum[row][g]   (B_*S_ rows)
// ---------------------------------------------------------------------------
__global__ __launch_bounds__(256)
void sumrows(const float* __restrict__ Psum, float* __restrict__ invs) {
  int i = blockIdx.x * 256 + threadIdx.x;
  const float4* p = (const float4*)(Psum + (long)i * 16);
  float4 a = p[0], b = p[1], c = p[2], d = p[3];
  float s = (a.x + a.y + a.z + a.w) + (b.x + b.y + b.z + b.w)
          + (c.x + c.y + c.z + c.w) + (d.x + d.y + d.z + d.w);
  invs[i] = 1.0f / s;
}

// ---------------------------------------------------------------------------
// gemm97: m97-replica bf16 B^T GEMM.  C[M,N] = A[M,K] @ B[N,K]^T (+epilogue).
//   BM=BN=128, BK=64, 4 waves (2x2; 64x64 per wave), 16x16x32 MFMA.
//   LDS 32 KB SINGLE buffer: A rows [0,8192) u16, B rows [8192,16384) u16,
//   row-major 64 u16 (128B) per row, 16B slot s of row r at s^(r&7) (T2).
//   Staging dest LINEAR (rule 21): group i (32 rows) at i*2048 + tid*8
//   == (i*32 + (tid>>3))*64 + (tid&7)*8; global src carries the inverse
//   slot permutation (st_ks).  [R7 bug: i*4096 spacing -> OOB; fixed.]
//   Loop: STAGE -> vmcnt(0)+syncthreads -> 16 ds_read_b128 + 32 MFMA
//   -> syncthreads.  Per-tile drain covered by ~3 co-resident blocks
//   (launch_bounds(256,3)) -- the m97/m114 implicit-TLP mechanism.
// ---------------------------------------------------------------------------
#define EPI_BF16_BIAS     0   // C u16 : v + bias[bz*sBias+col]
#define EPI_BF16_ROWSCALE 1   // C u16 : v * rowinv[bz*sBias+row]
#define EPI_F32_BIAS      2   // C f32 : v + bias[col]

template <int EPI>
__global__ __launch_bounds__(256, 3)
void gemm97(const u16* __restrict__ A, const u16* __restrict__ Bm,
            void* __restrict__ C, const float* __restrict__ bias,
            const float* __restrict__ rowinv,
            int M, int N, int K,
            long sA, long sB, long sC, long sBias,
            int nbx, int nby) {
  __shared__ u16 lds_[16384];   // A 8192 u16 | B 8192 u16

  const int tid = threadIdx.x;
  const int w = tid >> 6, l = tid & 63;
  const int wr = w >> 1, wc = w & 1;
  const int lr = l & 15, q = l >> 4;

  // T1 bijective XCD-chunk swizzle (grid % 8 == 0)
  const int flat = blockIdx.x;
  const int swz = (flat & 7) * ((int)gridDim.x >> 3) + (flat >> 3);
  const int bx = swz % nbx;
  const int rest = swz / nbx;
  const int by = rest % nby;
  const int bz = rest / nby;

  const long arow0 = (long)by * 128;
  const long bcol0 = (long)bx * 128;
  const u16* Ab = A + bz * sA + arow0 * K;
  const u16* Bb = Bm + bz * sB + bcol0 * K;
  const int nt = K >> 6;

  const int st_r = tid >> 3;                 // 0..31 row within 32-row group
  const int st_ks = (tid & 7) ^ (st_r & 7);  // swizzled global k-slot

  floatx4 acc[4][4] = {};

  for (int t = 0; t < nt; ++t) {
    const long k0 = (long)t << 6;
#pragma unroll
    for (int i = 0; i < 4; ++i)
      GLOAD(Ab + (long)(i * 32 + st_r) * K + k0 + st_ks * 8,
            &lds_[i * 2048 + tid * 8]);
#pragma unroll
    for (int i = 0; i < 4; ++i)
      GLOAD(Bb + (long)(i * 32 + st_r) * K + k0 + st_ks * 8,
            &lds_[8192 + i * 2048 + tid * 8]);
    WAITVM0();         // own stores landed before barrier
    __syncthreads();

    bf16x8 a[4][2], b[4][2];
#pragma unroll
    for (int m = 0; m < 4; ++m)
#pragma unroll
      for (int kk = 0; kk < 2; ++kk) {
        const int r = wr * 64 + m * 16 + lr, s = kk * 4 + q;
        a[m][kk] = *(const bf16x8*)&lds_[r * 64 + ((s ^ (r & 7)) * 8)];
      }
#pragma unroll
    for (int n = 0; n < 4; ++n)
#pragma unroll
      for (int kk = 0; kk < 2; ++kk) {
        const int c = wc * 64 + n * 16 + lr, s = kk * 4 + q;
        b[n][kk] = *(const bf16x8*)&lds_[8192 + c * 64 + ((s ^ (c & 7)) * 8)];
      }
#pragma unroll
    for (int kk = 0; kk < 2; ++kk)
#pragma unroll
      for (int n = 0; n < 4; ++n)
#pragma unroll
        for (int m = 0; m < 4; ++m)
          acc[m][n] = __builtin_amdgcn_mfma_f32_16x16x32_bf16(
              a[m][kk], b[n][kk], acc[m][n], 0, 0, 0);
    __syncthreads();
  }

  // epilogue. C/D layout: col = l&15, row = (l>>4)*4 + reg  [m89]
  const int r4 = q * 4;
#pragma unroll
  for (int mf = 0; mf < 4; ++mf)
#pragma unroll
    for (int nf = 0; nf < 4; ++nf)
#pragma unroll
      for (int r = 0; r < 4; ++r) {
        const long row = arow0 + wr * 64 + mf * 16 + r4 + r;
        const long col = bcol0 + wc * 64 + nf * 16 + lr;
        float v = acc[mf][nf][r];
        if constexpr (EPI == EPI_BF16_BIAS) {
          v += bias[bz * sBias + col];
          ((u16*)C)[bz * sC + row * N + col] = f2bf(v);
        } else if constexpr (EPI == EPI_BF16_ROWSCALE) {
          v *= rowinv[bz * sBias + row];
          ((u16*)C)[bz * sC + row * N + col] = f2bf(v);
        } else {  // EPI_F32_BIAS
          v += bias[col];
          ((float*)C)[bz * sC + row * N + col] = v;
        }
      }
}

// ---------------------------------------------------------------------------
// pexp128: same m97 structure, K=1024 (nt=16, unrolled), computing
//   P = exp((Q @ K^T)/32) masked->0 (bf16) + per-block row partial sums.
// Mask prefetched INSIDE the K-loop: tile t loads the 4 nf-cols of the
// thread's row-index t (16 rows/thread, exactly nt tiles), packed into 2
// u32 bitmasks -- absorbed into the per-tile drain, removing the 67 MB
// serial epilogue mask read.
// ---------------------------------------------------------------------------
__global__ __launch_bounds__(256, 3)
void pexp128(const u16* __restrict__ Q, const u16* __restrict__ Kb_,
             u16* __restrict__ P, const int* __restrict__ mask,
             float* __restrict__ Psum) {
  __shared__ u16 lds_[16384];

  const int tid = threadIdx.x;
  const int w = tid >> 6, l = tid & 63;
  const int wr = w >> 1, wc = w & 1;
  const int lr = l & 15, q = l >> 4;

  // T1 swizzle; grid 1024 = nbx16 x nby16 x z4
  const int flat = blockIdx.x;
  const int swz = (flat & 7) * ((int)gridDim.x >> 3) + (flat >> 3);
  const int bx = swz & 15;
  const int rest = swz >> 4;
  const int by = rest & 15;
  const int bz = rest >> 4;

  const long arow0 = (long)by * 128;
  const long bcol0 = (long)bx * 128;
  const int K = DH;
  const u16* Ab = Q + (long)bz * S_ * DH + arow0 * K;
  const u16* Bb = Kb_ + (long)bz * S_ * DH + bcol0 * K;
  const int* mb = mask + (long)bz * S_ * S_;

  const int st_r = tid >> 3;
  const int st_ks = (tid & 7) ^ (st_r & 7);

  floatx4 acc[4][4] = {};
  u32 mb0 = 0, mb1 = 0;

#pragma unroll
  for (int t = 0; t < 16; ++t) {
    const long k0 = (long)t << 6;
#pragma unroll
    for (int i = 0; i < 4; ++i)
      GLOAD(Ab + (long)(i * 32 + st_r) * K + k0 + st_ks * 8,
            &lds_[i * 2048 + tid * 8]);
#pragma unroll
    for (int i = 0; i < 4; ++i)
      GLOAD(Bb + (long)(i * 32 + st_r) * K + k0 + st_ks * 8,
            &lds_[8192 + i * 2048 + tid * 8]);
    // mask prefetch: tile t covers this thread's row (mf = t>>2, r = t&3)
    int mk[4];
    {
      const long row = arow0 + wr * 64 + (t >> 2) * 16 + q * 4 + (t & 3);
#pragma unroll
      for (int nf = 0; nf < 4; ++nf) {
        const long col = bcol0 + wc * 64 + nf * 16 + lr;
        mk[nf] = mb[row * S_ + col];
      }
    }
    WAITVM0();         // LDS-bound stores + mask loads landed
    __syncthreads();
#pragma unroll
    for (int nf = 0; nf < 4; ++nf) {
      const u32 bit = (mk[nf] != 0) ? 1u : 0u;
      if (t < 8) mb0 |= bit << (t * 4 + nf);
      else       mb1 |= bit << ((t - 8) * 4 + nf);
    }

    bf16x8 a[4][2], b[4][2];
#pragma unroll
    for (int m = 0; m < 4; ++m)
#pragma unroll
      for (int kk = 0; kk < 2; ++kk) {
        const int r = wr * 64 + m * 16 + lr, s = kk * 4 + q;
        a[m][kk] = *(const bf16x8*)&lds_[r * 64 + ((s ^ (r & 7)) * 8)];
      }
#pragma unroll
    for (int n = 0; n < 4; ++n)
#pragma unroll
      for (int kk = 0; kk < 2; ++kk) {
        const int c = wc * 64 + n * 16 + lr, s = kk * 4 + q;
        b[n][kk] = *(const bf16x8*)&lds_[8192 + c * 64 + ((s ^ (c & 7)) * 8)];
      }
#pragma unroll
    for (int kk = 0; kk < 2; ++kk)
#pragma unroll
      for (int n = 0; n < 4; ++n)
#pragma unroll
        for (int m = 0; m < 4; ++m)
          acc[m][n] = __builtin_amdgcn_mfma_f32_16x16x32_bf16(
              a[m][kk], b[n][kk], acc[m][n], 0, 0, 0);
    __syncthreads();
  }

  // epilogue: p = bit ? exp(v/32) : 0; bf16 store; row partial sums.
  const int r4 = q * 4;
  float rsum[4][4];
#pragma unroll
  for (int mf = 0; mf < 4; ++mf)
#pragma unroll
    for (int r = 0; r < 4; ++r) rsum[mf][r] = 0.f;

#pragma unroll
  for (int mf = 0; mf < 4; ++mf)
#pragma unroll
    for (int r = 0; r < 4; ++r) {
      const int trow = mf * 4 + r;            // == tile index that loaded it
      const long row = arow0 + wr * 64 + mf * 16 + r4 + r;
#pragma unroll
      for (int nf = 0; nf < 4; ++nf) {
        const int bit = trow < 8 ? (int)((mb0 >> (trow * 4 + nf)) & 1u)
                                 : (int)((mb1 >> ((trow - 8) * 4 + nf)) & 1u);
        const long col = bcol0 + wc * 64 + nf * 16 + lr;
        float p = 0.f;
        if (bit) p = __expf(acc[mf][nf][r] * 0.03125f);
        P[(long)bz * S_ * S_ + row * S_ + col] = f2bf(p);
        rsum[mf][r] += p;
      }
    }

  // reduce over the 16 lr-lanes, then across the 2 wc waves via LDS
  float* sc = (float*)lds_;   // [128 rows][2 wc] f32 (K-loop LDS is dead)
#pragma unroll
  for (int mf = 0; mf < 4; ++mf)
#pragma unroll
    for (int r = 0; r < 4; ++r) {
      float s = rsum[mf][r];
      s += __shfl_xor(s, 1); s += __shfl_xor(s, 2);
      s += __shfl_xor(s, 4); s += __shfl_xor(s, 8);
      if (lr == 0) sc[(wr * 64 + mf * 16 + r4 + r) * 2 + wc] = s;
    }
  __syncthreads();
  if (tid < 128) {
    float tot = sc[tid * 2] + sc[tid * 2 + 1];
    Psum[((long)bz * S_ + arow0 + tid) * 16 + bx] = tot;
  }
}

// ---------------------------------------------------------------------------
extern "C" void kernel_launch(void* const* d_in, const int* in_sizes, int n_in,
                              void* d_out, int out_size, void* d_ws, size_t ws_size,
                              hipStream_t stream) {
  const float* q    = (const float*)d_in[0];
  const float* k    = (const float*)d_in[1];
  const float* v    = (const float*)d_in[2];
  const int*   mask = (const int*)d_in[3];
  const float* Wq   = (const float*)d_in[4];
  const float* bq   = (const float*)d_in[5];
  const float* Wk   = (const float*)d_in[6];
  const float* bk   = (const float*)d_in[7];
  const float* Wv   = (const float*)d_in[8];
  const float* bv   = (const float*)d_in[9];
  const float* Wo   = (const float*)d_in[10];
  const float* bo   = (const float*)d_in[11];

  const long BS = (long)B_ * S_;      // 8192
  const long nQ = BS * DH;            // 8,388,608
  const long nW = (long)DH * DIN;     // 1,048,576
  const long nE = (long)B_ * S_ * S_; // 16,777,216

  char* ws = (char*)d_ws;
  size_t off = 0;
  auto alloc = [&](size_t bytes) {
    void* p = ws + off; off += (bytes + 255) & ~(size_t)255; return p;
  };

  // NOTE: qb..wob must stay CONTIGUOUS in this order (cast_all assumes it);
  // Qb,Kbf,Vb contiguous (proj z-batch output).
  u16* qb   = (u16*)alloc(nQ * 2);
  u16* kb   = (u16*)alloc(nQ * 2);
  u16* vb   = (u16*)alloc(nQ * 2);
  u16* wqb  = (u16*)alloc(nW * 2);
  u16* wkb  = (u16*)alloc(nW * 2);
  u16* wvb  = (u16*)alloc(nW * 2);
  u16* wob  = (u16*)alloc(nW * 2);
  u16* Qb   = (u16*)alloc(nQ * 2);
  u16* Kbf  = (u16*)alloc(nQ * 2);
  u16* Vb   = (u16*)alloc(nQ * 2);
  u16* VT   = (u16*)alloc(nQ * 2);
  u16* P    = (u16*)alloc(nE * 2);           // exp(e) unnormalized, bf16
  float* Psum = (float*)alloc(BS * 16 * 4);  // per-block row partials
  float* invs = (float*)alloc(BS * 4);       // 1/rowsum
  float* bcat = (float*)alloc(3 * DH * 4);
  u16* Yb  = vb;  // attention output aliases vb (consumed by proj)
  (void)kb; (void)wkb; (void)wvb;

  // 1. fused casts + bias gather
  cast_all<<<dim3(28672), 256, 0, stream>>>(q, k, v, Wq, Wk, Wv, Wo, qb);
  gather_bias<<<dim3(12), 256, 0, stream>>>(bq, bk, bv, bcat);

  // 2. QKV projections, z=3: grid 8x64x3 = 1536 (6 blocks/CU, ~3 resident)
  gemm97<EPI_BF16_BIAS><<<dim3(1536), 256, 0, stream>>>(qb, wqb, Qb, bcat,
      nullptr, (int)BS, DH, DIN, nQ, nW, nQ, DH, 8, 64);

  // 3. V -> V^T per batch
  {
    dim3 g(DH / 32, S_ / 32, B_);
    transpose_bf16<<<g, 256, 0, stream>>>(Vb, VT);
  }

  // 4. P = exp((Q K^T)/32) masked->0 + row partials: grid 16x16x4 = 1024
  pexp128<<<dim3(1024), 256, 0, stream>>>(Qb, Kbf, P, mask, Psum);

  // 5. row-sum reciprocals
  sumrows<<<dim3(32), 256, 0, stream>>>(Psum, invs);

  // 6. Y = (P @ V) * rowinv == P[S,S] @ VT[DH,S]^T: grid 8x16x4 = 512
  gemm97<EPI_BF16_ROWSCALE><<<dim3(512), 256, 0, stream>>>(P, VT, Yb,
      nullptr, invs, S_, DH, S_,
      (long)S_ * S_, (long)DH * S_, (long)S_ * DH, S_, 8, 16);

  // 7. out = Y @ Wo^T + bo -> fp32 d_out: grid 8x64 = 512
  gemm97<EPI_F32_BIAS><<<dim3(512), 256, 0, stream>>>(Yb, wob, d_out, bo,
      nullptr, (int)BS, DOUT, DH, 0, 0, 0, 0, 8, 64);
}

// Round 9
// 245.907 us; speedup vs baseline: 1.1451x; 1.0870x over previous
//
#include <hip/hip_runtime.h>
#include <hip/hip_bf16.h>

// Problem constants (from reference)
#define B_   4
#define S_   2048
#define DIN  1024
#define DH   1024
#define DOUT 1024

typedef __attribute__((ext_vector_type(8))) __bf16 bf16x8;
typedef __attribute__((ext_vector_type(4))) float floatx4;
typedef unsigned short u16;
typedef unsigned int u32;
typedef unsigned long long u64;

__device__ inline u16 f2bf(float f) {
  union { float f; u32 u; } x; x.f = f;
  u32 r = x.u + 0x7fffu + ((x.u >> 16) & 1u);  // RTNE
  return (u16)(r >> 16);
}

#define GLOAD(SRC, DST) __builtin_amdgcn_global_load_lds(                     \
    (const __attribute__((address_space(1))) u32*)(SRC),                      \
    (__attribute__((address_space(3))) u32*)(DST), 16, 0, 0)
#define WAITVM0() asm volatile("s_waitcnt vmcnt(0)" ::: "memory")

// ---------------------------------------------------------------------------
// Fused fp32 -> bf16 cast for all 7 tensors (dst regions contiguous in ws)
// ---------------------------------------------------------------------------
__global__ __launch_bounds__(256)
void cast_all(const float* __restrict__ q, const float* __restrict__ k,
              const float* __restrict__ v, const float* __restrict__ w0,
              const float* __restrict__ w1, const float* __restrict__ w2,
              const float* __restrict__ w3, u16* __restrict__ dst) {
  const long nQ = (long)B_ * S_ * DIN;   // 8,388,608
  const long nW = (long)DH * DIN;        // 1,048,576
  long b = blockIdx.x;
  const float* src; long doff;
  if (b < 8192)       { src = q;  doff = 0;            }
  else if (b < 16384) { src = k;  doff = nQ;     b -= 8192;  }
  else if (b < 24576) { src = v;  doff = 2 * nQ; b -= 16384; }
  else if (b < 25600) { src = w0; doff = 3 * nQ; b -= 24576; }
  else if (b < 26624) { src = w1; doff = 3 * nQ + nW;     b -= 25600; }
  else if (b < 27648) { src = w2; doff = 3 * nQ + 2 * nW; b -= 26624; }
  else                { src = w3; doff = 3 * nQ + 3 * nW; b -= 27648; }
  long i = b * 256 + threadIdx.x;        // float4 index within region
  float4 vv = ((const float4*)src)[i];
  ushort4 o;
  o.x = f2bf(vv.x); o.y = f2bf(vv.y); o.z = f2bf(vv.z); o.w = f2bf(vv.w);
  ((ushort4*)(dst + doff))[i] = o;
}

// ---------------------------------------------------------------------------
// mask_pack: int32 mask -> bitmask. Wave reads 64 consecutive ints
// (coalesced), __ballot(mk!=0), lane 0 stores the u64.  67MB -> 2MB.
// Bit l of the u64 <-> int (base+l); little-endian store => u32 word
// (idx>>5) has bit (idx&31).  16,777,216 ints / 256 = 65536 blocks.
// ---------------------------------------------------------------------------
__global__ __launch_bounds__(256)
void mask_pack(const int* __restrict__ mask, u64* __restrict__ packed) {
  const long i = (long)blockIdx.x * 256 + threadIdx.x;
  const int mk = mask[i];
  const u64 bal = __ballot(mk != 0);
  if ((threadIdx.x & 63) == 0) packed[i >> 6] = bal;
}

// ---------------------------------------------------------------------------
// gather 3 bias vectors into one contiguous [3][DH] buffer
// ---------------------------------------------------------------------------
__global__ __launch_bounds__(256)
void gather_bias(const float* __restrict__ b0, const float* __restrict__ b1,
                 const float* __restrict__ b2, float* __restrict__ dst) {
  int i = blockIdx.x * 256 + threadIdx.x;
  if (i < DH) dst[i] = b0[i];
  else if (i < 2 * DH) dst[i] = b1[i - DH];
  else if (i < 3 * DH) dst[i] = b2[i - 2 * DH];
}

// ---------------------------------------------------------------------------
// bf16 32x32-tile transpose (V -> V^T so PV becomes a B^T GEMM)
// ---------------------------------------------------------------------------
__global__ __launch_bounds__(256)
void transpose_bf16(const u16* __restrict__ in, u16* __restrict__ out) {
  __shared__ u16 t[32][33];
  const int b = blockIdx.z;
  const int r0 = blockIdx.y * 32, c0 = blockIdx.x * 32;
  const int tx = threadIdx.x & 31, ty = threadIdx.x >> 5;  // 32 x 8
  const u16* ib = in + (long)b * S_ * DH;
  u16* ob = out + (long)b * DH * S_;
#pragma unroll
  for (int i = 0; i < 4; ++i) {
    int r = ty + i * 8;
    t[r][tx] = ib[(long)(r0 + r) * DH + (c0 + tx)];
  }
  __syncthreads();
#pragma unroll
  for (int i = 0; i < 4; ++i) {
    int r = ty + i * 8;
    ob[(long)(c0 + r) * S_ + (r0 + tx)] = t[tx][r];
  }
}

// ---------------------------------------------------------------------------
// sumrows: invs[row] = 1 / sum_{g<16} Psum[row][g]   (B_*S_ rows)
// ---------------------------------------------------------------------------
__global__ __launch_bounds__(256)
void sumrows(const float* __restrict__ Psum, float* __restrict__ invs) {
  int i = blockIdx.x * 256 + threadIdx.x;
  const float4* p = (const float4*)(Psum + (long)i * 16);
  float4 a = p[0], b = p[1], c = p[2], d = p[3];
  float s = (a.x + a.y + a.z + a.w) + (b.x + b.y + b.z + b.w)
          + (c.x + c.y + c.z + c.w) + (d.x + d.y + d.z + d.w);
  invs[i] = 1.0f / s;
}

// ---------------------------------------------------------------------------
// gemm97: m97-replica bf16 B^T GEMM.  C[M,N] = A[M,K] @ B[N,K]^T (+epilogue).
//   BM=BN=128, BK=64, 4 waves (2x2; 64x64 per wave), 16x16x32 MFMA.
//   LDS 32 KB SINGLE buffer, XOR-swizzled slots (T2); staging dest LINEAR
//   (rule 21), global src carries the inverse slot permutation.
//   Loop: STAGE -> vmcnt(0)+syncthreads -> 16 ds_read_b128 + 32 MFMA
//   -> syncthreads.  Drain covered by ~3 co-resident blocks (m97/m114 TLP).
// ---------------------------------------------------------------------------
#define EPI_BF16_BIAS     0   // C u16 : v + bias[bz*sBias+col]
#define EPI_BF16_ROWSCALE 1   // C u16 : v * rowinv[bz*sBias+row]
#define EPI_F32_BIAS      2   // C f32 : v + bias[col]

template <int EPI>
__global__ __launch_bounds__(256, 3)
void gemm97(const u16* __restrict__ A, const u16* __restrict__ Bm,
            void* __restrict__ C, const float* __restrict__ bias,
            const float* __restrict__ rowinv,
            int M, int N, int K,
            long sA, long sB, long sC, long sBias,
            int nbx, int nby) {
  __shared__ u16 lds_[16384];   // A 8192 u16 | B 8192 u16

  const int tid = threadIdx.x;
  const int w = tid >> 6, l = tid & 63;
  const int wr = w >> 1, wc = w & 1;
  const int lr = l & 15, q = l >> 4;

  // T1 bijective XCD-chunk swizzle (grid % 8 == 0)
  const int flat = blockIdx.x;
  const int swz = (flat & 7) * ((int)gridDim.x >> 3) + (flat >> 3);
  const int bx = swz % nbx;
  const int rest = swz / nbx;
  const int by = rest % nby;
  const int bz = rest / nby;

  const long arow0 = (long)by * 128;
  const long bcol0 = (long)bx * 128;
  const u16* Ab = A + bz * sA + arow0 * K;
  const u16* Bb = Bm + bz * sB + bcol0 * K;
  const int nt = K >> 6;

  const int st_r = tid >> 3;                 // 0..31 row within 32-row group
  const int st_ks = (tid & 7) ^ (st_r & 7);  // swizzled global k-slot

  floatx4 acc[4][4] = {};

  for (int t = 0; t < nt; ++t) {
    const long k0 = (long)t << 6;
#pragma unroll
    for (int i = 0; i < 4; ++i)
      GLOAD(Ab + (long)(i * 32 + st_r) * K + k0 + st_ks * 8,
            &lds_[i * 2048 + tid * 8]);
#pragma unroll
    for (int i = 0; i < 4; ++i)
      GLOAD(Bb + (long)(i * 32 + st_r) * K + k0 + st_ks * 8,
            &lds_[8192 + i * 2048 + tid * 8]);
    WAITVM0();         // own stores landed before barrier
    __syncthreads();

    bf16x8 a[4][2], b[4][2];
#pragma unroll
    for (int m = 0; m < 4; ++m)
#pragma unroll
      for (int kk = 0; kk < 2; ++kk) {
        const int r = wr * 64 + m * 16 + lr, s = kk * 4 + q;
        a[m][kk] = *(const bf16x8*)&lds_[r * 64 + ((s ^ (r & 7)) * 8)];
      }
#pragma unroll
    for (int n = 0; n < 4; ++n)
#pragma unroll
      for (int kk = 0; kk < 2; ++kk) {
        const int c = wc * 64 + n * 16 + lr, s = kk * 4 + q;
        b[n][kk] = *(const bf16x8*)&lds_[8192 + c * 64 + ((s ^ (c & 7)) * 8)];
      }
#pragma unroll
    for (int kk = 0; kk < 2; ++kk)
#pragma unroll
      for (int n = 0; n < 4; ++n)
#pragma unroll
        for (int m = 0; m < 4; ++m)
          acc[m][n] = __builtin_amdgcn_mfma_f32_16x16x32_bf16(
              a[m][kk], b[n][kk], acc[m][n], 0, 0, 0);
    __syncthreads();
  }

  // epilogue. C/D layout: col = l&15, row = (l>>4)*4 + reg  [m89]
  const int r4 = q * 4;
#pragma unroll
  for (int mf = 0; mf < 4; ++mf)
#pragma unroll
    for (int nf = 0; nf < 4; ++nf)
#pragma unroll
      for (int r = 0; r < 4; ++r) {
        const long row = arow0 + wr * 64 + mf * 16 + r4 + r;
        const long col = bcol0 + wc * 64 + nf * 16 + lr;
        float v = acc[mf][nf][r];
        if constexpr (EPI == EPI_BF16_BIAS) {
          v += bias[bz * sBias + col];
          ((u16*)C)[bz * sC + row * N + col] = f2bf(v);
        } else if constexpr (EPI == EPI_BF16_ROWSCALE) {
          v *= rowinv[bz * sBias + row];
          ((u16*)C)[bz * sC + row * N + col] = f2bf(v);
        } else {  // EPI_F32_BIAS
          v += bias[col];
          ((float*)C)[bz * sC + row * N + col] = v;
        }
      }
}

// ---------------------------------------------------------------------------
// pexp128: m97-structure GEMM (K=1024, nt=16) computing
//   P = exp((Q @ K^T)/32) masked->0 (bf16) + per-block row partial sums.
// K-loop is PURE GEMM (R8's in-loop cold-HBM mask prefetch serialized the
// vmcnt(0) drain -- 100us, MfmaUtil 13%).  Mask now comes from the 2MB
// packed bitmask: epilogue coop-loads the block's 512 u32 words (2KB) into
// dead LDS, then bit-tests locally.
// ---------------------------------------------------------------------------
__global__ __launch_bounds__(256, 3)
void pexp128(const u16* __restrict__ Q, const u16* __restrict__ Kb_,
             u16* __restrict__ P, const u32* __restrict__ packed,
             float* __restrict__ Psum) {
  __shared__ u16 lds_[16384];

  const int tid = threadIdx.x;
  const int w = tid >> 6, l = tid & 63;
  const int wr = w >> 1, wc = w & 1;
  const int lr = l & 15, q = l >> 4;

  // T1 swizzle; grid 1024 = nbx16 x nby16 x z4
  const int flat = blockIdx.x;
  const int swz = (flat & 7) * ((int)gridDim.x >> 3) + (flat >> 3);
  const int bx = swz & 15;
  const int rest = swz >> 4;
  const int by = rest & 15;
  const int bz = rest >> 4;

  const long arow0 = (long)by * 128;
  const long bcol0 = (long)bx * 128;
  const int K = DH;
  const u16* Ab = Q + (long)bz * S_ * DH + arow0 * K;
  const u16* Bb = Kb_ + (long)bz * S_ * DH + bcol0 * K;

  const int st_r = tid >> 3;
  const int st_ks = (tid & 7) ^ (st_r & 7);

  floatx4 acc[4][4] = {};

#pragma unroll 4
  for (int t = 0; t < 16; ++t) {
    const long k0 = (long)t << 6;
#pragma unroll
    for (int i = 0; i < 4; ++i)
      GLOAD(Ab + (long)(i * 32 + st_r) * K + k0 + st_ks * 8,
            &lds_[i * 2048 + tid * 8]);
#pragma unroll
    for (int i = 0; i < 4; ++i)
      GLOAD(Bb + (long)(i * 32 + st_r) * K + k0 + st_ks * 8,
            &lds_[8192 + i * 2048 + tid * 8]);
    WAITVM0();
    __syncthreads();

    bf16x8 a[4][2], b[4][2];
#pragma unroll
    for (int m = 0; m < 4; ++m)
#pragma unroll
      for (int kk = 0; kk < 2; ++kk) {
        const int r = wr * 64 + m * 16 + lr, s = kk * 4 + q;
        a[m][kk] = *(const bf16x8*)&lds_[r * 64 + ((s ^ (r & 7)) * 8)];
      }
#pragma unroll
    for (int n = 0; n < 4; ++n)
#pragma unroll
      for (int kk = 0; kk < 2; ++kk) {
        const int c = wc * 64 + n * 16 + lr, s = kk * 4 + q;
        b[n][kk] = *(const bf16x8*)&lds_[8192 + c * 64 + ((s ^ (c & 7)) * 8)];
      }
#pragma unroll
    for (int kk = 0; kk < 2; ++kk)
#pragma unroll
      for (int n = 0; n < 4; ++n)
#pragma unroll
        for (int m = 0; m < 4; ++m)
          acc[m][n] = __builtin_amdgcn_mfma_f32_16x16x32_bf16(
              a[m][kk], b[n][kk], acc[m][n], 0, 0, 0);
    __syncthreads();
  }

  // ---- epilogue.
  // 1) coop-load the block's packed mask words: 128 rows x 4 u32 = 2KB into
  //    dead LDS at byte 16384.. (disjoint from Psum scratch at byte 0).
  u32* pw = (u32*)&lds_[8192];    // 512 u32
  {
    const u32* pg = packed + (long)bz * S_ * (S_ / 32)
                  + arow0 * (S_ / 32) + (bcol0 >> 5);
    const int lrow = tid >> 1;                 // 0..127
    const int j0 = (tid & 1) * 2;              // 0 or 2
    pw[lrow * 4 + j0]     = pg[(long)lrow * (S_ / 32) + j0];
    pw[lrow * 4 + j0 + 1] = pg[(long)lrow * (S_ / 32) + j0 + 1];
  }
  __syncthreads();

  // 2) p = bit ? exp(v/32) : 0; bf16 store; row partial sums.
  const int r4 = q * 4;
  float rsum[4][4];
#pragma unroll
  for (int mf = 0; mf < 4; ++mf)
#pragma unroll
    for (int r = 0; r < 4; ++r) rsum[mf][r] = 0.f;

#pragma unroll
  for (int mf = 0; mf < 4; ++mf)
#pragma unroll
    for (int r = 0; r < 4; ++r) {
      const int lrow = wr * 64 + mf * 16 + r4 + r;
      const long row = arow0 + lrow;
#pragma unroll
      for (int nf = 0; nf < 4; ++nf) {
        const u32 word = pw[lrow * 4 + wc * 2 + (nf >> 1)];
        const int bitpos = (nf & 1) * 16 + lr;
        const long col = bcol0 + wc * 64 + nf * 16 + lr;
        float p = 0.f;
        if ((word >> bitpos) & 1u) p = __expf(acc[mf][nf][r] * 0.03125f);
        P[(long)bz * S_ * S_ + row * S_ + col] = f2bf(p);
        rsum[mf][r] += p;
      }
    }
  __syncthreads();   // all bit-reads done before Psum scratch reuses LDS

  // 3) reduce over the 16 lr-lanes, then across the 2 wc waves via LDS
  float* sc = (float*)lds_;   // [128 rows][2 wc] f32 at byte 0 (disjoint)
#pragma unroll
  for (int mf = 0; mf < 4; ++mf)
#pragma unroll
    for (int r = 0; r < 4; ++r) {
      float s = rsum[mf][r];
      s += __shfl_xor(s, 1); s += __shfl_xor(s, 2);
      s += __shfl_xor(s, 4); s += __shfl_xor(s, 8);
      if (lr == 0) sc[(wr * 64 + mf * 16 + r4 + r) * 2 + wc] = s;
    }
  __syncthreads();
  if (tid < 128) {
    float tot = sc[tid * 2] + sc[tid * 2 + 1];
    Psum[((long)bz * S_ + arow0 + tid) * 16 + bx] = tot;
  }
}

// ---------------------------------------------------------------------------
extern "C" void kernel_launch(void* const* d_in, const int* in_sizes, int n_in,
                              void* d_out, int out_size, void* d_ws, size_t ws_size,
                              hipStream_t stream) {
  const float* q    = (const float*)d_in[0];
  const float* k    = (const float*)d_in[1];
  const float* v    = (const float*)d_in[2];
  const int*   mask = (const int*)d_in[3];
  const float* Wq   = (const float*)d_in[4];
  const float* bq   = (const float*)d_in[5];
  const float* Wk   = (const float*)d_in[6];
  const float* bk   = (const float*)d_in[7];
  const float* Wv   = (const float*)d_in[8];
  const float* bv   = (const float*)d_in[9];
  const float* Wo   = (const float*)d_in[10];
  const float* bo   = (const float*)d_in[11];

  const long BS = (long)B_ * S_;      // 8192
  const long nQ = BS * DH;            // 8,388,608
  const long nW = (long)DH * DIN;     // 1,048,576
  const long nE = (long)B_ * S_ * S_; // 16,777,216

  char* ws = (char*)d_ws;
  size_t off = 0;
  auto alloc = [&](size_t bytes) {
    void* p = ws + off; off += (bytes + 255) & ~(size_t)255; return p;
  };

  // NOTE: qb..wob must stay CONTIGUOUS in this order (cast_all assumes it);
  // Qb,Kbf,Vb contiguous (proj z-batch output).
  u16* qb   = (u16*)alloc(nQ * 2);
  u16* kb   = (u16*)alloc(nQ * 2);
  u16* vb   = (u16*)alloc(nQ * 2);
  u16* wqb  = (u16*)alloc(nW * 2);
  u16* wkb  = (u16*)alloc(nW * 2);
  u16* wvb  = (u16*)alloc(nW * 2);
  u16* wob  = (u16*)alloc(nW * 2);
  u16* Qb   = (u16*)alloc(nQ * 2);
  u16* Kbf  = (u16*)alloc(nQ * 2);
  u16* Vb   = (u16*)alloc(nQ * 2);
  u16* VT   = (u16*)alloc(nQ * 2);
  u16* P    = (u16*)alloc(nE * 2);           // exp(e) unnormalized, bf16
  u64* pk   = (u64*)alloc(nE / 8);           // packed mask bits (2MB)
  float* Psum = (float*)alloc(BS * 16 * 4);  // per-block row partials
  float* invs = (float*)alloc(BS * 4);       // 1/rowsum
  float* bcat = (float*)alloc(3 * DH * 4);
  u16* Yb  = vb;  // attention output aliases vb (consumed by proj)
  (void)kb; (void)wkb; (void)wvb;

  // 1. fused casts + mask pack + bias gather
  cast_all<<<dim3(28672), 256, 0, stream>>>(q, k, v, Wq, Wk, Wv, Wo, qb);
  mask_pack<<<dim3(65536), 256, 0, stream>>>(mask, pk);
  gather_bias<<<dim3(12), 256, 0, stream>>>(bq, bk, bv, bcat);

  // 2. QKV projections, z=3: grid 8x64x3 = 1536 (~3 resident blocks/CU)
  gemm97<EPI_BF16_BIAS><<<dim3(1536), 256, 0, stream>>>(qb, wqb, Qb, bcat,
      nullptr, (int)BS, DH, DIN, nQ, nW, nQ, DH, 8, 64);

  // 3. V -> V^T per batch
  {
    dim3 g(DH / 32, S_ / 32, B_);
    transpose_bf16<<<g, 256, 0, stream>>>(Vb, VT);
  }

  // 4. P = exp((Q K^T)/32) masked->0 + row partials: grid 16x16x4 = 1024
  pexp128<<<dim3(1024), 256, 0, stream>>>(Qb, Kbf, P, (const u32*)pk, Psum);

  // 5. row-sum reciprocals
  sumrows<<<dim3(32), 256, 0, stream>>>(Psum, invs);

  // 6. Y = (P @ V) * rowinv == P[S,S] @ VT[DH,S]^T: grid 8x16x4 = 512
  gemm97<EPI_BF16_ROWSCALE><<<dim3(512), 256, 0, stream>>>(P, VT, Yb,
      nullptr, invs, S_, DH, S_,
      (long)S_ * S_, (long)DH * S_, (long)S_ * DH, S_, 8, 16);

  // 7. out = Y @ Wo^T + bo -> fp32 d_out: grid 8x64 = 512
  gemm97<EPI_F32_BIAS><<<dim3(512), 256, 0, stream>>>(Yb, wob, d_out, bo,
      nullptr, (int)BS, DOUT, DH, 0, 0, 0, 0, 8, 64);
}

// Round 10
// 233.230 us; speedup vs baseline: 1.2073x; 1.0544x over previous
//
#include <hip/hip_runtime.h>
#include <hip/hip_bf16.h>

// Problem constants (from reference)
#define B_   4
#define S_   2048
#define DIN  1024
#define DH   1024
#define DOUT 1024

typedef __attribute__((ext_vector_type(8))) __bf16 bf16x8;
typedef __attribute__((ext_vector_type(4))) float floatx4;
typedef unsigned short u16;
typedef unsigned int u32;
typedef unsigned long long u64;

__device__ inline u16 f2bf(float f) {
  union { float f; u32 u; } x; x.f = f;
  u32 r = x.u + 0x7fffu + ((x.u >> 16) & 1u);  // RTNE
  return (u16)(r >> 16);
}

#define GLOAD(SRC, DST) __builtin_amdgcn_global_load_lds(                     \
    (const __attribute__((address_space(1))) u32*)(SRC),                      \
    (__attribute__((address_space(3))) u32*)(DST), 16, 0, 0)
#define WAITVM0() asm volatile("s_waitcnt vmcnt(0)" ::: "memory")

// ---------------------------------------------------------------------------
// prep: ONE launch doing (a) fp32->bf16 cast of q,k,v,Wq,Wk,Wv,Wo into the
// contiguous ws region, (b) mask int32 -> 2MB bitmask via __ballot,
// (c) bias gather into bcat[3][DH].  Block-range dispatch:
//   [0, 28672)        cast  (1024 f32/block)
//   [28672, 94208)    pack  (256 ints/block)
//   [94208, 94220)    bias
// ---------------------------------------------------------------------------
__global__ __launch_bounds__(256)
void prep(const float* __restrict__ q, const float* __restrict__ k,
          const float* __restrict__ v, const float* __restrict__ w0,
          const float* __restrict__ w1, const float* __restrict__ w2,
          const float* __restrict__ w3, u16* __restrict__ dst,
          const int* __restrict__ mask, u64* __restrict__ packed,
          const float* __restrict__ b0, const float* __restrict__ b1,
          const float* __restrict__ b2, float* __restrict__ bcat) {
  const long nQ = (long)B_ * S_ * DIN;   // 8,388,608
  const long nW = (long)DH * DIN;        // 1,048,576
  long b = blockIdx.x;
  if (b < 28672) {
    const float* src; long doff;
    if (b < 8192)       { src = q;  doff = 0;            }
    else if (b < 16384) { src = k;  doff = nQ;     b -= 8192;  }
    else if (b < 24576) { src = v;  doff = 2 * nQ; b -= 16384; }
    else if (b < 25600) { src = w0; doff = 3 * nQ; b -= 24576; }
    else if (b < 26624) { src = w1; doff = 3 * nQ + nW;     b -= 25600; }
    else if (b < 27648) { src = w2; doff = 3 * nQ + 2 * nW; b -= 26624; }
    else                { src = w3; doff = 3 * nQ + 3 * nW; b -= 27648; }
    long i = b * 256 + threadIdx.x;      // float4 index within region
    float4 vv = ((const float4*)src)[i];
    ushort4 o;
    o.x = f2bf(vv.x); o.y = f2bf(vv.y); o.z = f2bf(vv.z); o.w = f2bf(vv.w);
    ((ushort4*)(dst + doff))[i] = o;
  } else if (b < 94208) {
    const long i = (b - 28672) * 256 + threadIdx.x;
    const int mk = mask[i];
    const u64 bal = __ballot(mk != 0);
    if ((threadIdx.x & 63) == 0) packed[i >> 6] = bal;
  } else {
    int i = (int)(b - 94208) * 256 + threadIdx.x;
    if (i < DH) bcat[i] = b0[i];
    else if (i < 2 * DH) bcat[i] = b1[i - DH];
    else if (i < 3 * DH) bcat[i] = b2[i - 2 * DH];
  }
}

// ---------------------------------------------------------------------------
// bf16 32x32-tile transpose (V -> V^T so PV becomes a B^T GEMM)
// ---------------------------------------------------------------------------
__global__ __launch_bounds__(256)
void transpose_bf16(const u16* __restrict__ in, u16* __restrict__ out) {
  __shared__ u16 t[32][33];
  const int b = blockIdx.z;
  const int r0 = blockIdx.y * 32, c0 = blockIdx.x * 32;
  const int tx = threadIdx.x & 31, ty = threadIdx.x >> 5;  // 32 x 8
  const u16* ib = in + (long)b * S_ * DH;
  u16* ob = out + (long)b * DH * S_;
#pragma unroll
  for (int i = 0; i < 4; ++i) {
    int r = ty + i * 8;
    t[r][tx] = ib[(long)(r0 + r) * DH + (c0 + tx)];
  }
  __syncthreads();
#pragma unroll
  for (int i = 0; i < 4; ++i) {
    int r = ty + i * 8;
    ob[(long)(c0 + r) * S_ + (r0 + tx)] = t[tx][r];
  }
}

// ---------------------------------------------------------------------------
// gemm97: m97-replica bf16 B^T GEMM.  C[M,N] = A[M,K] @ B[N,K]^T (+epilogue).
//   BM=BN=128, BK=64, 4 waves (2x2; 64x64 per wave), 16x16x32 MFMA.
//   LDS 32 KB SINGLE buffer, XOR-swizzled slots (T2); staging dest LINEAR
//   (rule 21), global src carries the inverse slot permutation.
//   Loop: STAGE -> vmcnt(0)+syncthreads -> 16 ds_read_b128 + 32 MFMA
//   -> syncthreads.  launch_bounds(256,4): VGPR<=128 (need 64) -> 4 blocks
//   resident/CU (128KB LDS), doubling the R9 TLP that covers the drain.
//   EPI_BF16_ROWSCALE computes 1/rowsum from Psum in a tiny prologue
//   (sumrows kernel folded in).
// ---------------------------------------------------------------------------
#define EPI_BF16_BIAS     0   // C u16 : v + bias[bz*sBias+col]
#define EPI_BF16_ROWSCALE 1   // C u16 : v / rowsum  (rowsum from Psum[.,16])
#define EPI_F32_BIAS      2   // C f32 : v + bias[col]

template <int EPI>
__global__ __launch_bounds__(256, 4)
void gemm97(const u16* __restrict__ A, const u16* __restrict__ Bm,
            void* __restrict__ C, const float* __restrict__ bias,
            const float* __restrict__ Psum,
            int M, int N, int K,
            long sA, long sB, long sC, long sBias,
            int nbx, int nby) {
  __shared__ u16 lds_[16384];   // A 8192 u16 | B 8192 u16
  __shared__ float invs_s[(EPI == EPI_BF16_ROWSCALE) ? 128 : 1];

  const int tid = threadIdx.x;
  const int w = tid >> 6, l = tid & 63;
  const int wr = w >> 1, wc = w & 1;
  const int lr = l & 15, q = l >> 4;

  // T1 bijective XCD-chunk swizzle (grid % 8 == 0)
  const int flat = blockIdx.x;
  const int swz = (flat & 7) * ((int)gridDim.x >> 3) + (flat >> 3);
  const int bx = swz % nbx;
  const int rest = swz / nbx;
  const int by = rest % nby;
  const int bz = rest / nby;

  const long arow0 = (long)by * 128;
  const long bcol0 = (long)bx * 128;
  const u16* Ab = A + bz * sA + arow0 * K;
  const u16* Bb = Bm + bz * sB + bcol0 * K;
  const int nt = K >> 6;

  if constexpr (EPI == EPI_BF16_ROWSCALE) {
    // prologue: invs for this block's 128 rows (64B/thread, coalesced)
    if (tid < 128) {
      const float4* p = (const float4*)(Psum + ((long)bz * S_ + arow0 + tid) * 16);
      float4 a = p[0], b = p[1], c = p[2], d = p[3];
      float s = (a.x + a.y + a.z + a.w) + (b.x + b.y + b.z + b.w)
              + (c.x + c.y + c.z + c.w) + (d.x + d.y + d.z + d.w);
      invs_s[tid] = 1.0f / s;
    }
    // visibility guaranteed by the K-loop barriers before epilogue reads
  }

  const int st_r = tid >> 3;                 // 0..31 row within 32-row group
  const int st_ks = (tid & 7) ^ (st_r & 7);  // swizzled global k-slot

  floatx4 acc[4][4] = {};

  for (int t = 0; t < nt; ++t) {
    const long k0 = (long)t << 6;
#pragma unroll
    for (int i = 0; i < 4; ++i)
      GLOAD(Ab + (long)(i * 32 + st_r) * K + k0 + st_ks * 8,
            &lds_[i * 2048 + tid * 8]);
#pragma unroll
    for (int i = 0; i < 4; ++i)
      GLOAD(Bb + (long)(i * 32 + st_r) * K + k0 + st_ks * 8,
            &lds_[8192 + i * 2048 + tid * 8]);
    WAITVM0();         // own stores landed before barrier
    __syncthreads();

    bf16x8 a[4][2], b[4][2];
#pragma unroll
    for (int m = 0; m < 4; ++m)
#pragma unroll
      for (int kk = 0; kk < 2; ++kk) {
        const int r = wr * 64 + m * 16 + lr, s = kk * 4 + q;
        a[m][kk] = *(const bf16x8*)&lds_[r * 64 + ((s ^ (r & 7)) * 8)];
      }
#pragma unroll
    for (int n = 0; n < 4; ++n)
#pragma unroll
      for (int kk = 0; kk < 2; ++kk) {
        const int c = wc * 64 + n * 16 + lr, s = kk * 4 + q;
        b[n][kk] = *(const bf16x8*)&lds_[8192 + c * 64 + ((s ^ (c & 7)) * 8)];
      }
#pragma unroll
    for (int kk = 0; kk < 2; ++kk)
#pragma unroll
      for (int n = 0; n < 4; ++n)
#pragma unroll
        for (int m = 0; m < 4; ++m)
          acc[m][n] = __builtin_amdgcn_mfma_f32_16x16x32_bf16(
              a[m][kk], b[n][kk], acc[m][n], 0, 0, 0);
    __syncthreads();
  }

  // epilogue. C/D layout: col = l&15, row = (l>>4)*4 + reg  [m89]
  const int r4 = q * 4;
#pragma unroll
  for (int mf = 0; mf < 4; ++mf)
#pragma unroll
    for (int nf = 0; nf < 4; ++nf)
#pragma unroll
      for (int r = 0; r < 4; ++r) {
        const long row = arow0 + wr * 64 + mf * 16 + r4 + r;
        const long col = bcol0 + wc * 64 + nf * 16 + lr;
        float v = acc[mf][nf][r];
        if constexpr (EPI == EPI_BF16_BIAS) {
          v += bias[bz * sBias + col];
          ((u16*)C)[bz * sC + row * N + col] = f2bf(v);
        } else if constexpr (EPI == EPI_BF16_ROWSCALE) {
          v *= invs_s[wr * 64 + mf * 16 + r4 + r];
          ((u16*)C)[bz * sC + row * N + col] = f2bf(v);
        } else {  // EPI_F32_BIAS
          v += bias[col];
          ((float*)C)[bz * sC + row * N + col] = v;
        }
      }
}

// ---------------------------------------------------------------------------
// pexp128: m97-structure GEMM (K=1024, nt=16) computing
//   P = exp((Q @ K^T)/32) masked->0 (bf16) + per-block row partial sums.
// K-loop is PURE GEMM; mask bits come from the 2MB packed bitmask, coop-
// loaded (2KB) into dead LDS in the epilogue.  launch_bounds(256,4):
// grid 1024 = exactly 4 blocks/CU resident.
// ---------------------------------------------------------------------------
__global__ __launch_bounds__(256, 4)
void pexp128(const u16* __restrict__ Q, const u16* __restrict__ Kb_,
             u16* __restrict__ P, const u32* __restrict__ packed,
             float* __restrict__ Psum) {
  __shared__ u16 lds_[16384];

  const int tid = threadIdx.x;
  const int w = tid >> 6, l = tid & 63;
  const int wr = w >> 1, wc = w & 1;
  const int lr = l & 15, q = l >> 4;

  // T1 swizzle; grid 1024 = nbx16 x nby16 x z4
  const int flat = blockIdx.x;
  const int swz = (flat & 7) * ((int)gridDim.x >> 3) + (flat >> 3);
  const int bx = swz & 15;
  const int rest = swz >> 4;
  const int by = rest & 15;
  const int bz = rest >> 4;

  const long arow0 = (long)by * 128;
  const long bcol0 = (long)bx * 128;
  const int K = DH;
  const u16* Ab = Q + (long)bz * S_ * DH + arow0 * K;
  const u16* Bb = Kb_ + (long)bz * S_ * DH + bcol0 * K;

  const int st_r = tid >> 3;
  const int st_ks = (tid & 7) ^ (st_r & 7);

  floatx4 acc[4][4] = {};

#pragma unroll 4
  for (int t = 0; t < 16; ++t) {
    const long k0 = (long)t << 6;
#pragma unroll
    for (int i = 0; i < 4; ++i)
      GLOAD(Ab + (long)(i * 32 + st_r) * K + k0 + st_ks * 8,
            &lds_[i * 2048 + tid * 8]);
#pragma unroll
    for (int i = 0; i < 4; ++i)
      GLOAD(Bb + (long)(i * 32 + st_r) * K + k0 + st_ks * 8,
            &lds_[8192 + i * 2048 + tid * 8]);
    WAITVM0();
    __syncthreads();

    bf16x8 a[4][2], b[4][2];
#pragma unroll
    for (int m = 0; m < 4; ++m)
#pragma unroll
      for (int kk = 0; kk < 2; ++kk) {
        const int r = wr * 64 + m * 16 + lr, s = kk * 4 + q;
        a[m][kk] = *(const bf16x8*)&lds_[r * 64 + ((s ^ (r & 7)) * 8)];
      }
#pragma unroll
    for (int n = 0; n < 4; ++n)
#pragma unroll
      for (int kk = 0; kk < 2; ++kk) {
        const int c = wc * 64 + n * 16 + lr, s = kk * 4 + q;
        b[n][kk] = *(const bf16x8*)&lds_[8192 + c * 64 + ((s ^ (c & 7)) * 8)];
      }
#pragma unroll
    for (int kk = 0; kk < 2; ++kk)
#pragma unroll
      for (int n = 0; n < 4; ++n)
#pragma unroll
        for (int m = 0; m < 4; ++m)
          acc[m][n] = __builtin_amdgcn_mfma_f32_16x16x32_bf16(
              a[m][kk], b[n][kk], acc[m][n], 0, 0, 0);
    __syncthreads();
  }

  // ---- epilogue.
  // 1) coop-load packed mask words: 128 rows x 4 u32 = 2KB into dead LDS
  //    at byte 16384.. (disjoint from Psum scratch at byte 0).
  u32* pw = (u32*)&lds_[8192];    // 512 u32
  {
    const u32* pg = packed + (long)bz * S_ * (S_ / 32)
                  + arow0 * (S_ / 32) + (bcol0 >> 5);
    const int lrow = tid >> 1;                 // 0..127
    const int j0 = (tid & 1) * 2;              // 0 or 2
    pw[lrow * 4 + j0]     = pg[(long)lrow * (S_ / 32) + j0];
    pw[lrow * 4 + j0 + 1] = pg[(long)lrow * (S_ / 32) + j0 + 1];
  }
  __syncthreads();

  // 2) p = bit ? exp(v/32) : 0; bf16 store; row partial sums.
  const int r4 = q * 4;
  float rsum[4][4];
#pragma unroll
  for (int mf = 0; mf < 4; ++mf)
#pragma unroll
    for (int r = 0; r < 4; ++r) rsum[mf][r] = 0.f;

#pragma unroll
  for (int mf = 0; mf < 4; ++mf)
#pragma unroll
    for (int r = 0; r < 4; ++r) {
      const int lrow = wr * 64 + mf * 16 + r4 + r;
      const long row = arow0 + lrow;
#pragma unroll
      for (int nf = 0; nf < 4; ++nf) {
        const u32 word = pw[lrow * 4 + wc * 2 + (nf >> 1)];
        const int bitpos = (nf & 1) * 16 + lr;
        const long col = bcol0 + wc * 64 + nf * 16 + lr;
        float p = 0.f;
        if ((word >> bitpos) & 1u) p = __expf(acc[mf][nf][r] * 0.03125f);
        P[(long)bz * S_ * S_ + row * S_ + col] = f2bf(p);
        rsum[mf][r] += p;
      }
    }
  __syncthreads();   // all bit-reads done before Psum scratch reuses LDS

  // 3) reduce over the 16 lr-lanes, then across the 2 wc waves via LDS
  float* sc = (float*)lds_;   // [128 rows][2 wc] f32 at byte 0 (disjoint)
#pragma unroll
  for (int mf = 0; mf < 4; ++mf)
#pragma unroll
    for (int r = 0; r < 4; ++r) {
      float s = rsum[mf][r];
      s += __shfl_xor(s, 1); s += __shfl_xor(s, 2);
      s += __shfl_xor(s, 4); s += __shfl_xor(s, 8);
      if (lr == 0) sc[(wr * 64 + mf * 16 + r4 + r) * 2 + wc] = s;
    }
  __syncthreads();
  if (tid < 128) {
    float tot = sc[tid * 2] + sc[tid * 2 + 1];
    Psum[((long)bz * S_ + arow0 + tid) * 16 + bx] = tot;
  }
}

// ---------------------------------------------------------------------------
extern "C" void kernel_launch(void* const* d_in, const int* in_sizes, int n_in,
                              void* d_out, int out_size, void* d_ws, size_t ws_size,
                              hipStream_t stream) {
  const float* q    = (const float*)d_in[0];
  const float* k    = (const float*)d_in[1];
  const float* v    = (const float*)d_in[2];
  const int*   mask = (const int*)d_in[3];
  const float* Wq   = (const float*)d_in[4];
  const float* bq   = (const float*)d_in[5];
  const float* Wk   = (const float*)d_in[6];
  const float* bk   = (const float*)d_in[7];
  const float* Wv   = (const float*)d_in[8];
  const float* bv   = (const float*)d_in[9];
  const float* Wo   = (const float*)d_in[10];
  const float* bo   = (const float*)d_in[11];

  const long BS = (long)B_ * S_;      // 8192
  const long nQ = BS * DH;            // 8,388,608
  const long nW = (long)DH * DIN;     // 1,048,576
  const long nE = (long)B_ * S_ * S_; // 16,777,216

  char* ws = (char*)d_ws;
  size_t off = 0;
  auto alloc = [&](size_t bytes) {
    void* p = ws + off; off += (bytes + 255) & ~(size_t)255; return p;
  };

  // NOTE: qb..wob must stay CONTIGUOUS in this order (prep assumes it);
  // Qb,Kbf,Vb contiguous (proj z-batch output).
  u16* qb   = (u16*)alloc(nQ * 2);
  u16* kb   = (u16*)alloc(nQ * 2);
  u16* vb   = (u16*)alloc(nQ * 2);
  u16* wqb  = (u16*)alloc(nW * 2);
  u16* wkb  = (u16*)alloc(nW * 2);
  u16* wvb  = (u16*)alloc(nW * 2);
  u16* wob  = (u16*)alloc(nW * 2);
  u16* Qb   = (u16*)alloc(nQ * 2);
  u16* Kbf  = (u16*)alloc(nQ * 2);
  u16* Vb   = (u16*)alloc(nQ * 2);
  u16* VT   = (u16*)alloc(nQ * 2);
  u16* P    = (u16*)alloc(nE * 2);           // exp(e) unnormalized, bf16
  u64* pk   = (u64*)alloc(nE / 8);           // packed mask bits (2MB)
  float* Psum = (float*)alloc(BS * 16 * 4);  // per-block row partials
  float* bcat = (float*)alloc(3 * DH * 4);
  u16* Yb  = vb;  // attention output aliases vb (consumed by proj)
  (void)kb; (void)wkb; (void)wvb;

  // 1. fused prep: casts + mask pack + bias gather (one launch)
  prep<<<dim3(94220), 256, 0, stream>>>(q, k, v, Wq, Wk, Wv, Wo, qb,
                                        mask, pk, bq, bk, bv, bcat);

  // 2. QKV projections, z=3: grid 8x64x3 = 1536
  gemm97<EPI_BF16_BIAS><<<dim3(1536), 256, 0, stream>>>(qb, wqb, Qb, bcat,
      nullptr, (int)BS, DH, DIN, nQ, nW, nQ, DH, 8, 64);

  // 3. V -> V^T per batch
  {
    dim3 g(DH / 32, S_ / 32, B_);
    transpose_bf16<<<g, 256, 0, stream>>>(Vb, VT);
  }

  // 4. P = exp((Q K^T)/32) masked->0 + row partials: grid 16x16x4 = 1024
  pexp128<<<dim3(1024), 256, 0, stream>>>(Qb, Kbf, P, (const u32*)pk, Psum);

  // 5. Y = (P @ V) / rowsum == P[S,S] @ VT[DH,S]^T: grid 8x16x4 = 512
  //    (rowsum reduction folded into the kernel prologue from Psum)
  gemm97<EPI_BF16_ROWSCALE><<<dim3(512), 256, 0, stream>>>(P, VT, Yb,
      nullptr, Psum, S_, DH, S_,
      (long)S_ * S_, (long)DH * S_, (long)S_ * DH, 0, 8, 16);

  // 6. out = Y @ Wo^T + bo -> fp32 d_out: grid 8x64 = 512
  gemm97<EPI_F32_BIAS><<<dim3(512), 256, 0, stream>>>(Yb, wob, d_out, bo,
      nullptr, (int)BS, DOUT, DH, 0, 0, 0, 0, 8, 64);
}

// Round 11
// 229.281 us; speedup vs baseline: 1.2281x; 1.0172x over previous
//
#include <hip/hip_runtime.h>
#include <hip/hip_bf16.h>

// Problem constants (from reference)
#define B_   4
#define S_   2048
#define DIN  1024
#define DH   1024
#define DOUT 1024

typedef __attribute__((ext_vector_type(8))) __bf16 bf16x8;
typedef __attribute__((ext_vector_type(4))) float floatx4;
typedef unsigned short u16;
typedef unsigned int u32;
typedef unsigned long long u64;

__device__ inline u16 f2bf(float f) {
  union { float f; u32 u; } x; x.f = f;
  u32 r = x.u + 0x7fffu + ((x.u >> 16) & 1u);  // RTNE
  return (u16)(r >> 16);
}

#define GLOAD(SRC, DST) __builtin_amdgcn_global_load_lds(                     \
    (const __attribute__((address_space(1))) u32*)(SRC),                      \
    (__attribute__((address_space(3))) u32*)(DST), 16, 0, 0)
#define WAITVM0() asm volatile("s_waitcnt vmcnt(0)" ::: "memory")

// ---------------------------------------------------------------------------
// prep: ONE grid-stride launch (1804 blocks -- R10's 94220 single-shot blocks
// ran at 1.9 TB/s, latency-bound; Guideline 11).
//   blocks [0,1536):    fp32->bf16 cast of q,k,v,Wq,Wk,Wv,Wo (float4/lane,
//                       ~19 independent iterations/thread)
//   blocks [1536,1792): mask int32 -> packed bits.  int4/lane (16B), 4x
//                       __ballot per wave-iter, 64 iters/thread.
//                       Layout: granule g = 256 consecutive ints -> 4 u64:
//                       packed[g*4+j] bit l  <->  mask[g*256 + 4*l + j]
//   blocks [1792,1804): bias gather into bcat[3][DH]
// ---------------------------------------------------------------------------
__global__ __launch_bounds__(256)
void prep(const float* __restrict__ q, const float* __restrict__ k,
          const float* __restrict__ v, const float* __restrict__ w0,
          const float* __restrict__ w1, const float* __restrict__ w2,
          const float* __restrict__ w3, u16* __restrict__ dst,
          const int* __restrict__ mask, u64* __restrict__ packed,
          const float* __restrict__ b0, const float* __restrict__ b1,
          const float* __restrict__ b2, float* __restrict__ bcat) {
  const long nQ = (long)B_ * S_ * DIN;     // 8,388,608 elems
  const long nW = (long)DH * DIN;          // 1,048,576 elems
  const long nQ4 = nQ >> 2;                // 2^21 float4
  const long nW4 = nW >> 2;                // 2^18 float4
  const int b = blockIdx.x;

  if (b < 1536) {
    const long total4 = 3 * nQ4 + 4 * nW4;      // 7,340,032
    for (long i = (long)b * 256 + threadIdx.x; i < total4; i += 1536L * 256) {
      const float* src; long doff, idx;
      if (i < nQ4)               { src = q;  doff = 0;          idx = i; }
      else if (i < 2 * nQ4)      { src = k;  doff = nQ;         idx = i - nQ4; }
      else if (i < 3 * nQ4)      { src = v;  doff = 2 * nQ;     idx = i - 2 * nQ4; }
      else {
        long j = i - 3 * nQ4;
        if (j < nW4)             { src = w0; doff = 3 * nQ;          idx = j; }
        else if (j < 2 * nW4)    { src = w1; doff = 3 * nQ + nW;     idx = j - nW4; }
        else if (j < 3 * nW4)    { src = w2; doff = 3 * nQ + 2 * nW; idx = j - 2 * nW4; }
        else                     { src = w3; doff = 3 * nQ + 3 * nW; idx = j - 3 * nW4; }
      }
      float4 vv = ((const float4*)src)[idx];
      ushort4 o;
      o.x = f2bf(vv.x); o.y = f2bf(vv.y); o.z = f2bf(vv.z); o.w = f2bf(vv.w);
      ((ushort4*)(dst + doff))[idx] = o;
    }
  } else if (b < 1792) {
    // 4,194,304 int4s / 65536 threads = 64 full iterations (no tail)
    const long nI4 = ((long)B_ * S_ * S_) >> 2;
    for (long f = (long)(b - 1536) * 256 + threadIdx.x; f < nI4; f += 256L * 256) {
      int4 m4 = ((const int4*)mask)[f];
      u64 bal0 = __ballot(m4.x != 0);
      u64 bal1 = __ballot(m4.y != 0);
      u64 bal2 = __ballot(m4.z != 0);
      u64 bal3 = __ballot(m4.w != 0);
      if ((threadIdx.x & 63) == 0) {
        const long g = f >> 6;            // wave-uniform (f_base % 64 == 0)
        ulonglong2 p01; p01.x = bal0; p01.y = bal1;
        ulonglong2 p23; p23.x = bal2; p23.y = bal3;
        ((ulonglong2*)(packed + g * 4))[0] = p01;
        ((ulonglong2*)(packed + g * 4))[1] = p23;
      }
    }
  } else {
    int i = (b - 1792) * 256 + threadIdx.x;
    if (i < DH) bcat[i] = b0[i];
    else if (i < 2 * DH) bcat[i] = b1[i - DH];
    else if (i < 3 * DH) bcat[i] = b2[i - 2 * DH];
  }
}

// ---------------------------------------------------------------------------
// bf16 32x32-tile transpose (V -> V^T so PV becomes a B^T GEMM)
// ---------------------------------------------------------------------------
__global__ __launch_bounds__(256)
void transpose_bf16(const u16* __restrict__ in, u16* __restrict__ out) {
  __shared__ u16 t[32][33];
  const int b = blockIdx.z;
  const int r0 = blockIdx.y * 32, c0 = blockIdx.x * 32;
  const int tx = threadIdx.x & 31, ty = threadIdx.x >> 5;  // 32 x 8
  const u16* ib = in + (long)b * S_ * DH;
  u16* ob = out + (long)b * DH * S_;
#pragma unroll
  for (int i = 0; i < 4; ++i) {
    int r = ty + i * 8;
    t[r][tx] = ib[(long)(r0 + r) * DH + (c0 + tx)];
  }
  __syncthreads();
#pragma unroll
  for (int i = 0; i < 4; ++i) {
    int r = ty + i * 8;
    ob[(long)(c0 + r) * S_ + (r0 + tx)] = t[tx][r];
  }
}

// ---------------------------------------------------------------------------
// gemm97: m97-replica bf16 B^T GEMM.  C[M,N] = A[M,K] @ B[N,K]^T (+epilogue).
//   BM=BN=128, BK=64, 4 waves (2x2; 64x64 per wave), 16x16x32 MFMA.
//   LDS 32 KB SINGLE buffer, XOR-swizzled slots (T2); staging dest LINEAR
//   (rule 21), global src carries the inverse slot permutation.
//   launch_bounds(256,4): 4 blocks/CU resident cover the per-tile drain.
//   EPI_BF16_ROWSCALE computes 1/rowsum from Psum in a tiny prologue.
// ---------------------------------------------------------------------------
#define EPI_BF16_BIAS     0   // C u16 : v + bias[bz*sBias+col]
#define EPI_BF16_ROWSCALE 1   // C u16 : v / rowsum  (rowsum from Psum[.,16])
#define EPI_F32_BIAS      2   // C f32 : v + bias[col]

template <int EPI>
__global__ __launch_bounds__(256, 4)
void gemm97(const u16* __restrict__ A, const u16* __restrict__ Bm,
            void* __restrict__ C, const float* __restrict__ bias,
            const float* __restrict__ Psum,
            int M, int N, int K,
            long sA, long sB, long sC, long sBias,
            int nbx, int nby) {
  __shared__ u16 lds_[16384];   // A 8192 u16 | B 8192 u16
  __shared__ float invs_s[(EPI == EPI_BF16_ROWSCALE) ? 128 : 1];

  const int tid = threadIdx.x;
  const int w = tid >> 6, l = tid & 63;
  const int wr = w >> 1, wc = w & 1;
  const int lr = l & 15, q = l >> 4;

  // T1 bijective XCD-chunk swizzle (grid % 8 == 0)
  const int flat = blockIdx.x;
  const int swz = (flat & 7) * ((int)gridDim.x >> 3) + (flat >> 3);
  const int bx = swz % nbx;
  const int rest = swz / nbx;
  const int by = rest % nby;
  const int bz = rest / nby;

  const long arow0 = (long)by * 128;
  const long bcol0 = (long)bx * 128;
  const u16* Ab = A + bz * sA + arow0 * K;
  const u16* Bb = Bm + bz * sB + bcol0 * K;
  const int nt = K >> 6;

  if constexpr (EPI == EPI_BF16_ROWSCALE) {
    // prologue: invs for this block's 128 rows (64B/thread, coalesced)
    if (tid < 128) {
      const float4* p = (const float4*)(Psum + ((long)bz * S_ + arow0 + tid) * 16);
      float4 a = p[0], b = p[1], c = p[2], d = p[3];
      float s = (a.x + a.y + a.z + a.w) + (b.x + b.y + b.z + b.w)
              + (c.x + c.y + c.z + c.w) + (d.x + d.y + d.z + d.w);
      invs_s[tid] = 1.0f / s;
    }
    // visibility guaranteed by the K-loop barriers before epilogue reads
  }

  const int st_r = tid >> 3;                 // 0..31 row within 32-row group
  const int st_ks = (tid & 7) ^ (st_r & 7);  // swizzled global k-slot

  floatx4 acc[4][4] = {};

  for (int t = 0; t < nt; ++t) {
    const long k0 = (long)t << 6;
#pragma unroll
    for (int i = 0; i < 4; ++i)
      GLOAD(Ab + (long)(i * 32 + st_r) * K + k0 + st_ks * 8,
            &lds_[i * 2048 + tid * 8]);
#pragma unroll
    for (int i = 0; i < 4; ++i)
      GLOAD(Bb + (long)(i * 32 + st_r) * K + k0 + st_ks * 8,
            &lds_[8192 + i * 2048 + tid * 8]);
    WAITVM0();         // own stores landed before barrier
    __syncthreads();

    bf16x8 a[4][2], b[4][2];
#pragma unroll
    for (int m = 0; m < 4; ++m)
#pragma unroll
      for (int kk = 0; kk < 2; ++kk) {
        const int r = wr * 64 + m * 16 + lr, s = kk * 4 + q;
        a[m][kk] = *(const bf16x8*)&lds_[r * 64 + ((s ^ (r & 7)) * 8)];
      }
#pragma unroll
    for (int n = 0; n < 4; ++n)
#pragma unroll
      for (int kk = 0; kk < 2; ++kk) {
        const int c = wc * 64 + n * 16 + lr, s = kk * 4 + q;
        b[n][kk] = *(const bf16x8*)&lds_[8192 + c * 64 + ((s ^ (c & 7)) * 8)];
      }
#pragma unroll
    for (int kk = 0; kk < 2; ++kk)
#pragma unroll
      for (int n = 0; n < 4; ++n)
#pragma unroll
        for (int m = 0; m < 4; ++m)
          acc[m][n] = __builtin_amdgcn_mfma_f32_16x16x32_bf16(
              a[m][kk], b[n][kk], acc[m][n], 0, 0, 0);
    __syncthreads();
  }

  // epilogue. C/D layout: col = l&15, row = (l>>4)*4 + reg  [m89]
  const int r4 = q * 4;
#pragma unroll
  for (int mf = 0; mf < 4; ++mf)
#pragma unroll
    for (int nf = 0; nf < 4; ++nf)
#pragma unroll
      for (int r = 0; r < 4; ++r) {
        const long row = arow0 + wr * 64 + mf * 16 + r4 + r;
        const long col = bcol0 + wc * 64 + nf * 16 + lr;
        float v = acc[mf][nf][r];
        if constexpr (EPI == EPI_BF16_BIAS) {
          v += bias[bz * sBias + col];
          ((u16*)C)[bz * sC + row * N + col] = f2bf(v);
        } else if constexpr (EPI == EPI_BF16_ROWSCALE) {
          v *= invs_s[wr * 64 + mf * 16 + r4 + r];
          ((u16*)C)[bz * sC + row * N + col] = f2bf(v);
        } else {  // EPI_F32_BIAS
          v += bias[col];
          ((float*)C)[bz * sC + row * N + col] = v;
        }
      }
}

// ---------------------------------------------------------------------------
// pexp128: m97-structure GEMM (K=1024, nt=16) computing
//   P = exp((Q @ K^T)/32) masked->0 (bf16) + per-block row partial sums.
// K-loop is PURE GEMM; mask bits come from the 2MB packed bitmask
// (ballot-natural layout: packed[g*4+j] bit l <-> int g*256+4l+j),
// coop-loaded (2KB of u32 halves) into dead LDS in the epilogue.
// ---------------------------------------------------------------------------
__global__ __launch_bounds__(256, 4)
void pexp128(const u16* __restrict__ Q, const u16* __restrict__ Kb_,
             u16* __restrict__ P, const u32* __restrict__ packed,
             float* __restrict__ Psum) {
  __shared__ u16 lds_[16384];

  const int tid = threadIdx.x;
  const int w = tid >> 6, l = tid & 63;
  const int wr = w >> 1, wc = w & 1;
  const int lr = l & 15, q = l >> 4;

  // T1 swizzle; grid 1024 = nbx16 x nby16 x z4
  const int flat = blockIdx.x;
  const int swz = (flat & 7) * ((int)gridDim.x >> 3) + (flat >> 3);
  const int bx = swz & 15;
  const int rest = swz >> 4;
  const int by = rest & 15;
  const int bz = rest >> 4;

  const long arow0 = (long)by * 128;
  const long bcol0 = (long)bx * 128;
  const int K = DH;
  const u16* Ab = Q + (long)bz * S_ * DH + arow0 * K;
  const u16* Bb = Kb_ + (long)bz * S_ * DH + bcol0 * K;

  const int st_r = tid >> 3;
  const int st_ks = (tid & 7) ^ (st_r & 7);

  floatx4 acc[4][4] = {};

#pragma unroll 4
  for (int t = 0; t < 16; ++t) {
    const long k0 = (long)t << 6;
#pragma unroll
    for (int i = 0; i < 4; ++i)
      GLOAD(Ab + (long)(i * 32 + st_r) * K + k0 + st_ks * 8,
            &lds_[i * 2048 + tid * 8]);
#pragma unroll
    for (int i = 0; i < 4; ++i)
      GLOAD(Bb + (long)(i * 32 + st_r) * K + k0 + st_ks * 8,
            &lds_[8192 + i * 2048 + tid * 8]);
    WAITVM0();
    __syncthreads();

    bf16x8 a[4][2], b[4][2];
#pragma unroll
    for (int m = 0; m < 4; ++m)
#pragma unroll
      for (int kk = 0; kk < 2; ++kk) {
        const int r = wr * 64 + m * 16 + lr, s = kk * 4 + q;
        a[m][kk] = *(const bf16x8*)&lds_[r * 64 + ((s ^ (r & 7)) * 8)];
      }
#pragma unroll
    for (int n = 0; n < 4; ++n)
#pragma unroll
      for (int kk = 0; kk < 2; ++kk) {
        const int c = wc * 64 + n * 16 + lr, s = kk * 4 + q;
        b[n][kk] = *(const bf16x8*)&lds_[8192 + c * 64 + ((s ^ (c & 7)) * 8)];
      }
#pragma unroll
    for (int kk = 0; kk < 2; ++kk)
#pragma unroll
      for (int n = 0; n < 4; ++n)
#pragma unroll
        for (int m = 0; m < 4; ++m)
          acc[m][n] = __builtin_amdgcn_mfma_f32_16x16x32_bf16(
              a[m][kk], b[n][kk], acc[m][n], 0, 0, 0);
    __syncthreads();
  }

  // ---- epilogue.
  // 1) coop-load packed-mask u32 halves: for row = arow0+lrow, j = 0..3:
  //    pu idx = g*8 + j*2 + (bx&1), g = bz*16384 + row*8 + (bx>>1).
  //    128 rows x 4 u32 = 2KB into dead LDS at byte 16384.
  u32* pw = (u32*)&lds_[8192];    // 512 u32
  {
    const int half = bx & 1;
    const int lrow = tid >> 1;                 // 0..127
    const int j0 = (tid & 1) * 2;              // 0 or 2
    const long g = (long)bz * 16384 + (arow0 + lrow) * 8 + (bx >> 1);
    pw[lrow * 4 + j0]     = packed[g * 8 + j0 * 2 + half];
    pw[lrow * 4 + j0 + 1] = packed[g * 8 + (j0 + 1) * 2 + half];
  }
  __syncthreads();

  // 2) p = bit ? exp(v/32) : 0; bf16 store; row partial sums.
  //    word = pw[lrow*4 + (lr&3)], bit = wc*16 + nf*4 + (lr>>2).
  const int r4 = q * 4;
  float rsum[4][4];
#pragma unroll
  for (int mf = 0; mf < 4; ++mf)
#pragma unroll
    for (int r = 0; r < 4; ++r) rsum[mf][r] = 0.f;

#pragma unroll
  for (int mf = 0; mf < 4; ++mf)
#pragma unroll
    for (int r = 0; r < 4; ++r) {
      const int lrow = wr * 64 + mf * 16 + r4 + r;
      const long row = arow0 + lrow;
      const u32 word = pw[lrow * 4 + (lr & 3)];
#pragma unroll
      for (int nf = 0; nf < 4; ++nf) {
        const int bitpos = wc * 16 + nf * 4 + (lr >> 2);
        const long col = bcol0 + wc * 64 + nf * 16 + lr;
        float p = 0.f;
        if ((word >> bitpos) & 1u) p = __expf(acc[mf][nf][r] * 0.03125f);
        P[(long)bz * S_ * S_ + row * S_ + col] = f2bf(p);
        rsum[mf][r] += p;
      }
    }
  __syncthreads();   // all bit-reads done before Psum scratch reuses LDS

  // 3) reduce over the 16 lr-lanes, then across the 2 wc waves via LDS
  float* sc = (float*)lds_;   // [128 rows][2 wc] f32 at byte 0 (disjoint)
#pragma unroll
  for (int mf = 0; mf < 4; ++mf)
#pragma unroll
    for (int r = 0; r < 4; ++r) {
      float s = rsum[mf][r];
      s += __shfl_xor(s, 1); s += __shfl_xor(s, 2);
      s += __shfl_xor(s, 4); s += __shfl_xor(s, 8);
      if (lr == 0) sc[(wr * 64 + mf * 16 + r4 + r) * 2 + wc] = s;
    }
  __syncthreads();
  if (tid < 128) {
    float tot = sc[tid * 2] + sc[tid * 2 + 1];
    Psum[((long)bz * S_ + arow0 + tid) * 16 + bx] = tot;
  }
}

// ---------------------------------------------------------------------------
extern "C" void kernel_launch(void* const* d_in, const int* in_sizes, int n_in,
                              void* d_out, int out_size, void* d_ws, size_t ws_size,
                              hipStream_t stream) {
  const float* q    = (const float*)d_in[0];
  const float* k    = (const float*)d_in[1];
  const float* v    = (const float*)d_in[2];
  const int*   mask = (const int*)d_in[3];
  const float* Wq   = (const float*)d_in[4];
  const float* bq   = (const float*)d_in[5];
  const float* Wk   = (const float*)d_in[6];
  const float* bk   = (const float*)d_in[7];
  const float* Wv   = (const float*)d_in[8];
  const float* bv   = (const float*)d_in[9];
  const float* Wo   = (const float*)d_in[10];
  const float* bo   = (const float*)d_in[11];

  const long BS = (long)B_ * S_;      // 8192
  const long nQ = BS * DH;            // 8,388,608
  const long nW = (long)DH * DIN;     // 1,048,576
  const long nE = (long)B_ * S_ * S_; // 16,777,216

  char* ws = (char*)d_ws;
  size_t off = 0;
  auto alloc = [&](size_t bytes) {
    void* p = ws + off; off += (bytes + 255) & ~(size_t)255; return p;
  };

  // NOTE: qb..wob must stay CONTIGUOUS in this order (prep assumes it);
  // Qb,Kbf,Vb contiguous (proj z-batch output).
  u16* qb   = (u16*)alloc(nQ * 2);
  u16* kb   = (u16*)alloc(nQ * 2);
  u16* vb   = (u16*)alloc(nQ * 2);
  u16* wqb  = (u16*)alloc(nW * 2);
  u16* wkb  = (u16*)alloc(nW * 2);
  u16* wvb  = (u16*)alloc(nW * 2);
  u16* wob  = (u16*)alloc(nW * 2);
  u16* Qb   = (u16*)alloc(nQ * 2);
  u16* Kbf  = (u16*)alloc(nQ * 2);
  u16* Vb   = (u16*)alloc(nQ * 2);
  u16* VT   = (u16*)alloc(nQ * 2);
  u16* P    = (u16*)alloc(nE * 2);           // exp(e) unnormalized, bf16
  u64* pk   = (u64*)alloc(nE / 8);           // packed mask bits (2MB)
  float* Psum = (float*)alloc(BS * 16 * 4);  // per-block row partials
  float* bcat = (float*)alloc(3 * DH * 4);
  u16* Yb  = vb;  // attention output aliases vb (consumed by proj)
  (void)kb; (void)wkb; (void)wvb;

  // 1. fused prep: casts + mask pack + bias gather (grid-stride, 1804 blocks)
  prep<<<dim3(1804), 256, 0, stream>>>(q, k, v, Wq, Wk, Wv, Wo, qb,
                                       mask, pk, bq, bk, bv, bcat);

  // 2. QKV projections, z=3: grid 8x64x3 = 1536
  gemm97<EPI_BF16_BIAS><<<dim3(1536), 256, 0, stream>>>(qb, wqb, Qb, bcat,
      nullptr, (int)BS, DH, DIN, nQ, nW, nQ, DH, 8, 64);

  // 3. V -> V^T per batch
  {
    dim3 g(DH / 32, S_ / 32, B_);
    transpose_bf16<<<g, 256, 0, stream>>>(Vb, VT);
  }

  // 4. P = exp((Q K^T)/32) masked->0 + row partials: grid 16x16x4 = 1024
  pexp128<<<dim3(1024), 256, 0, stream>>>(Qb, Kbf, P, (const u32*)pk, Psum);

  // 5. Y = (P @ V) / rowsum == P[S,S] @ VT[DH,S]^T: grid 8x16x4 = 512
  //    (rowsum reduction folded into the kernel prologue from Psum)
  gemm97<EPI_BF16_ROWSCALE><<<dim3(512), 256, 0, stream>>>(P, VT, Yb,
      nullptr, Psum, S_, DH, S_,
      (long)S_ * S_, (long)DH * S_, (long)S_ * DH, 0, 8, 16);

  // 6. out = Y @ Wo^T + bo -> fp32 d_out: grid 8x64 = 512
  gemm97<EPI_F32_BIAS><<<dim3(512), 256, 0, stream>>>(Yb, wob, d_out, bo,
      nullptr, (int)BS, DOUT, DH, 0, 0, 0, 0, 8, 64);
}